// Round 8
// baseline (17662.900 us; speedup 1.0000x reference)
//
#include <hip/hip_runtime.h>
#include <hip/hip_bf16.h>
#include <math.h>

#define BB 256
#define SS 512
#define TT 511
#define HH 1024
#define EE 512
#define NC 10

typedef _Float16 f16;
typedef __attribute__((ext_vector_type(8))) _Float16 half8;
typedef __attribute__((ext_vector_type(4))) float f32x4;

#define LOSCALE 2048.0f
#define LOINV   (1.0f / 2048.0f)
#define LOINV2  (1.0f / (2048.0f * 2048.0f))

// workspace offsets (bytes); total ~21.2 MB
// W1/W2/W3: 4096 frags x 512 f16 = 4 MB EACH (R4-R7 bug: was spaced 2 MB -> overlap!)
#define W1_OFF    0u          // f16 W1 frags [4096][64][8]   4 MB
#define W2_OFF    4194304u    // f16 W2 frags (x2048)         4 MB
#define W3_OFF    8388608u    // f16 W3 frags (x2048^2)       4 MB
#define WO_OFF    12582912u   // f16 W_oh frags [2048][64][8] 2 MB
#define GIF_OFF   14680064u   // f32 [3][2048] gx tables i,f (f64-computed) 24 KB
#define GO_OFF    14704640u   // f32 [3][1024] gx table o                    12 KB
#define CAND_OFF  14716928u   // f32 [3][1024] sigmoid(gx_c)                 12 KB
#define XV_OFF    14729216u   // u8  [256][512]                             128 KB
#define C1_OFF    14860288u   // f16 [2][256][1024] c split 1                 1 MB
#define C2_OFF    15908864u   // f16 [2][256][1024] c split 2 (x2048)         1 MB
#define C3_OFF    16957440u   // f16 [2][256][1024] c split 3 (x2048^2)       1 MB
#define CF_OFF    18006016u   // f32 [2][256][1024] exact fp32 c carry        2 MB
#define HBUF_OFF  20103168u   // f32 [256][1024]                              1 MB
#define PBUF_OFF  21151744u   // f32 [256][10]
#define BAR_OFF   21161984u   // 8 domains * 256B

#define SMEM_BYTES (131072 + 24576)   // 128K W2 frags + 24K reduce

__global__ void k_xv(const int* __restrict__ x, unsigned char* __restrict__ xv) {
  int i = blockIdx.x * 256 + threadIdx.x;
  if (i < BB * SS) xv[i] = (unsigned char)x[i];
}

// gx tables in DOUBLE precision (rounded once to f32)
__global__ void k_tables(const float* __restrict__ emb,
                         const float* __restrict__ w_ix, const float* __restrict__ w_fx,
                         const float* __restrict__ w_ox, const float* __restrict__ w_cx,
                         const float* __restrict__ b_i, const float* __restrict__ b_f,
                         const float* __restrict__ b_o, const float* __restrict__ b_c,
                         float* __restrict__ Gif, float* __restrict__ Go,
                         float* __restrict__ Cand) {
  int idx = blockIdx.x * 256 + threadIdx.x;
  if (idx >= 3 * 4096) return;
  int v = idx >> 12, g = idx & 4095;
  const float* ev = emb + v * EE;
  const float* W; float bias; float* dst; bool sig = false; int j;
  if (g < 1024)      { j = g;        W = w_ix; bias = b_i[j]; dst = Gif + v * 2048 + j; }
  else if (g < 2048) { j = g - 1024; W = w_fx; bias = b_f[j]; dst = Gif + v * 2048 + 1024 + j; }
  else if (g < 3072) { j = g - 2048; W = w_ox; bias = b_o[j]; dst = Go + v * 1024 + j; }
  else               { j = g - 3072; W = w_cx; bias = b_c[j]; dst = Cand + v * 1024 + j; sig = true; }
  double s = (double)bias;
  for (int e = 0; e < EE; ++e) s = fma((double)ev[e], (double)W[e * HH + j], s);
  if (sig) s = 1.0 / (1.0 + exp(-s));
  *dst = (float)s;
}

// W triple-split frags for W_ih|W_fh (i|f packed in cols 0-7 / 8-15).
// frag f = (((slice*4+kq)*2+nh)*2+nn)*8+kc ; element (f*64+lane)*8+e
// k = kq*256+kc*32+(lane>>4)*8+e ; col=lane&15 ; jj = slice*32+nh*16+nn*8+(col&7)
// W = w1 + w2/2048 + w3/2048^2 EXACTLY (11+11+11 bits >= fp32 24-bit mantissa)
__global__ void k_fragw(const float* __restrict__ w_ih, const float* __restrict__ w_fh,
                        f16* __restrict__ d1, f16* __restrict__ d2, f16* __restrict__ d3) {
  int idx = blockIdx.x * 256 + threadIdx.x;
  if (idx >= 262144) return;
  int l = idx & 63;
  int kc = (idx >> 6) & 7, nn = (idx >> 9) & 1, nh = (idx >> 10) & 1,
      kq = (idx >> 11) & 3, slice = idx >> 13;
  int col = l & 15;
  int jj = slice * 32 + nh * 16 + nn * 8 + (col & 7);
  const float* W = (col < 8) ? w_ih : w_fh;
  int k0 = kq * 256 + kc * 32 + ((l >> 4) << 3);
  half8 o1, o2, o3;
  #pragma unroll
  for (int e = 0; e < 8; ++e) {
    float w = W[(k0 + e) * HH + jj];
    f16 h1 = (f16)w;
    float r1 = (w - (float)h1) * LOSCALE;    // exact (Sterbenz + pow2 scale)
    f16 h2 = (f16)r1;
    f16 h3 = (f16)((r1 - (float)h2) * LOSCALE);  // exact: residual fits f16
    o1[e] = h1; o2[e] = h2; o3[e] = h3;
  }
  size_t off = (size_t)idx * 8;
  *(half8*)(d1 + off) = o1;
  *(half8*)(d2 + off) = o2;
  *(half8*)(d3 + off) = o3;
}

// W_oh single-f16 frags: f = ((slice*4+kq)*2+nh)*8+kc ; jj = slice*32+nh*16+col
__global__ void k_frago(const float* __restrict__ w_oh, f16* __restrict__ dst) {
  int idx = blockIdx.x * 256 + threadIdx.x;
  if (idx >= 131072) return;
  int l = idx & 63;
  int kc = (idx >> 6) & 7, nh = (idx >> 9) & 1, kq = (idx >> 10) & 3, slice = idx >> 12;
  int col = l & 15;
  int jj = slice * 32 + nh * 16 + col;
  int k0 = kq * 256 + kc * 32 + ((l >> 4) << 3);
  half8 out;
  #pragma unroll
  for (int e = 0; e < 8; ++e) out[e] = (f16)w_oh[(k0 + e) * HH + jj];
  *(half8*)(dst + (size_t)idx * 8) = out;
}

__device__ __forceinline__ void domain_barrier(unsigned* cnt, unsigned* gen,
                                               unsigned nwg, unsigned& mygen) {
  __syncthreads();
  if (threadIdx.x == 0) {
    __threadfence();  // release c stores (agent scope)
    unsigned g = mygen;
    unsigned prev = __hip_atomic_fetch_add(cnt, 1u, __ATOMIC_ACQ_REL, __HIP_MEMORY_SCOPE_AGENT);
    if (prev == nwg - 1u) {
      __hip_atomic_store(cnt, 0u, __ATOMIC_RELAXED, __HIP_MEMORY_SCOPE_AGENT);
      __hip_atomic_store(gen, g + 1u, __ATOMIC_RELEASE, __HIP_MEMORY_SCOPE_AGENT);
    } else {
      while (__hip_atomic_load(gen, __ATOMIC_RELAXED, __HIP_MEMORY_SCOPE_AGENT) == g) {
        __builtin_amdgcn_s_sleep(2);
      }
    }
    __threadfence();  // acquire: invalidate stale caches
    mygen = g + 1u;
  }
  __syncthreads();
}

// persistent scan: 256 WGs x 512 thr (8 waves), 1 WG/CU (LDS 152K).
// waves: w = nh*4 + kq. Per wave: BOTH 16-row groups (mr), 16 cols (nh), K-quarter kq.
// c EXACT via triple split: gh = c1W1 + (c2W1+c1W2)*2^-11 + (c3W1+c2W2+c1W3)*2^-22
// (dropped terms <= 2^-33*|cW| — below gh's fp32 ulp). cf carries exact fp32 c.
__global__ __launch_bounds__(512, 2) void k_scan(
    const f16* __restrict__ W1g, const f16* __restrict__ W2g, const f16* __restrict__ W3g,
    const f16* __restrict__ Wo,
    const float* __restrict__ Gif, const float* __restrict__ Go,
    const float* __restrict__ Cand, const unsigned char* __restrict__ xv,
    f16* c1buf, f16* c2buf, f16* c3buf, float* cfbuf,
    float* __restrict__ hbuf, unsigned* bar) {
  extern __shared__ char smem[];
  f16*   W2s = (f16*)smem;                 // per-slice W2: [kq][nh][nn][kc][64][8] 128KB
  f32x4* Rs  = (f32x4*)(smem + 131072);    // [nh][q=3][mr][nn][64] = 24KB

  const int blk = blockIdx.x;
  const int dom = blk & 7;
  const int slice = blk >> 3;
  const int j0 = slice << 5;
  const int tid = threadIdx.x;
  const int lane = tid & 63;
  const int w = tid >> 6;
  const int kq = w & 3;
  const int nh = w >> 2;
  const int akoff = ((lane >> 4) << 3);
  const int rowA = dom * 32 + (lane & 15);   // A-row for mr=0; +16 for mr=1

  // preload this slice's W2 frags into LDS (128KB = 128 frags)
  {
    const half8* gsrc = (const half8*)(W2g + (size_t)slice * 65536);
    half8* ldst = (half8*)W2s;
    for (int i = tid; i < 8192; i += 512) ldst[i] = gsrc[i];
  }

  // W1, W3 in registers: per wave (kq,nh): nn(2) x kc(8) frags each = 64+64 VGPR
  half8 B1[8][2], B3[8][2];
  #pragma unroll
  for (int nn = 0; nn < 2; ++nn) {
    #pragma unroll
    for (int kc = 0; kc < 8; ++kc) {
      size_t f = ((((size_t)slice * 4 + kq) * 2 + nh) * 2 + nn) * 8 + kc;
      B1[kc][nn] = *(const half8*)(W1g + (f * 64 + lane) * 8);
      B3[kc][nn] = *(const half8*)(W3g + (f * 64 + lane) * 8);
    }
  }
  __syncthreads();

  const f16* w2Base = W2s + (kq * 2 + nh) * 8192 + lane * 8;  // + nn*4096 + kc*512

  unsigned mygen = 0;
  unsigned* bcnt = bar + dom * 64;
  unsigned* bgen = bar + dom * 64 + 16;

  for (int t = 0; t < TT; ++t) {
    const int pin = t & 1, pout = pin ^ 1;
    const f16* a1b = c1buf + (size_t)pin * (BB * HH) + rowA * HH + kq * 256 + akoff;
    const f16* a2b = c2buf + (size_t)pin * (BB * HH) + rowA * HH + kq * 256 + akoff;
    const f16* a3b = c3buf + (size_t)pin * (BB * HH) + rowA * HH + kq * 256 + akoff;
    const float* cfin = cfbuf + (size_t)pin * (BB * HH);
    f16* c1out = c1buf + (size_t)pout * (BB * HH);
    f16* c2out = c2buf + (size_t)pout * (BB * HH);
    f16* c3out = c3buf + (size_t)pout * (BB * HH);
    float* cfout = cfbuf + (size_t)pout * (BB * HH);

    f32x4 accA[2][2], accB[2][2], accC[2][2];   // [mr][nn]
    #pragma unroll
    for (int mr = 0; mr < 2; ++mr)
      #pragma unroll
      for (int nn = 0; nn < 2; ++nn) {
        accA[mr][nn] = (f32x4){0.f, 0.f, 0.f, 0.f};
        accB[mr][nn] = (f32x4){0.f, 0.f, 0.f, 0.f};
        accC[mr][nn] = (f32x4){0.f, 0.f, 0.f, 0.f};
      }
    #pragma unroll
    for (int kc = 0; kc < 8; ++kc) {
      half8 a1[2], a2[2], a3[2];
      #pragma unroll
      for (int mr = 0; mr < 2; ++mr) {
        a1[mr] = *(const half8*)(a1b + mr * 16 * HH + kc * 32);
        a2[mr] = *(const half8*)(a2b + mr * 16 * HH + kc * 32);
        a3[mr] = *(const half8*)(a3b + mr * 16 * HH + kc * 32);
      }
      #pragma unroll
      for (int nn = 0; nn < 2; ++nn) {
        half8 w2 = *(const half8*)(w2Base + nn * 4096 + kc * 512);
        #pragma unroll
        for (int mr = 0; mr < 2; ++mr) {
          accA[mr][nn] = __builtin_amdgcn_mfma_f32_16x16x32_f16(a1[mr], B1[kc][nn], accA[mr][nn], 0, 0, 0);
          accB[mr][nn] = __builtin_amdgcn_mfma_f32_16x16x32_f16(a2[mr], B1[kc][nn], accB[mr][nn], 0, 0, 0);
          accB[mr][nn] = __builtin_amdgcn_mfma_f32_16x16x32_f16(a1[mr], w2, accB[mr][nn], 0, 0, 0);
          accC[mr][nn] = __builtin_amdgcn_mfma_f32_16x16x32_f16(a3[mr], B1[kc][nn], accC[mr][nn], 0, 0, 0);
          accC[mr][nn] = __builtin_amdgcn_mfma_f32_16x16x32_f16(a2[mr], w2, accC[mr][nn], 0, 0, 0);
          accC[mr][nn] = __builtin_amdgcn_mfma_f32_16x16x32_f16(a1[mr], B3[kc][nn], accC[mr][nn], 0, 0, 0);
        }
      }
    }
    f32x4 gh[2][2];
    #pragma unroll
    for (int mr = 0; mr < 2; ++mr)
      #pragma unroll
      for (int nn = 0; nn < 2; ++nn)
        #pragma unroll
        for (int r = 0; r < 4; ++r)
          gh[mr][nn][r] = fmaf(accC[mr][nn][r], LOINV2,
                               fmaf(accB[mr][nn][r], LOINV, accA[mr][nn][r]));
    if (kq != 0) {
      #pragma unroll
      for (int mr = 0; mr < 2; ++mr)
        #pragma unroll
        for (int nn = 0; nn < 2; ++nn)
          Rs[(((nh * 3 + (kq - 1)) * 2 + mr) * 2 + nn) * 64 + lane] = gh[mr][nn];
    }
    __syncthreads();
    if (kq == 0) {
      #pragma unroll
      for (int q = 0; q < 3; ++q)
        #pragma unroll
        for (int mr = 0; mr < 2; ++mr)
          #pragma unroll
          for (int nn = 0; nn < 2; ++nn)
            gh[mr][nn] += Rs[(((nh * 3 + q) * 2 + mr) * 2 + nn) * 64 + lane];
      const int col = lane & 15;
      const bool isI = col < 8;
      const int jcol = col & 7;
      const int gofs = isI ? 0 : 1024;
      #pragma unroll
      for (int mr = 0; mr < 2; ++mr) {
        const int rbase = dom * 32 + mr * 16 + ((lane >> 4) << 2);
        unsigned v[4];
        #pragma unroll
        for (int r = 0; r < 4; ++r) v[r] = xv[(rbase + r) * SS + t];
        #pragma unroll
        for (int nn = 0; nn < 2; ++nn) {
          const int jj = j0 + nh * 16 + nn * 8 + jcol;
          float sg[4];
          #pragma unroll
          for (int r = 0; r < 4; ++r) {
            float pre = gh[mr][nn][r] + Gif[v[r] * 2048 + gofs + jj];
            sg[r] = 1.f / (1.f + expf(-pre));
          }
          float ot[4];
          #pragma unroll
          for (int r = 0; r < 4; ++r) ot[r] = __shfl_xor(sg[r], 8);
          const int rlo = isI ? 0 : 2;
          #pragma unroll
          for (int q = 0; q < 2; ++q) {
            int r = rlo + q;
            int b = rbase + r;
            float iv = isI ? sg[r] : ot[r];
            float fv = isI ? ot[r] : sg[r];
            float cd = Cand[v[r] * 1024 + jj];
            float co = cfin[b * HH + jj];              // exact fp32 carry
            float cn = fmaf(cd, iv, co * fv);
            cfout[b * HH + jj] = cn;
            f16 h1 = (f16)cn;
            float r1 = (cn - (float)h1) * LOSCALE;     // exact
            f16 h2 = (f16)r1;
            f16 h3 = (f16)((r1 - (float)h2) * LOSCALE); // exact residual
            c1out[b * HH + jj] = h1;
            c2out[b * HH + jj] = h2;
            c3out[b * HH + jj] = h3;
          }
        }
      }
    }
    domain_barrier(bcnt, bgen, 32u, mygen);
  }

  // ---- last step: o gate from c_510 (buf0, hi+lo), h = tanh(c_511)*o*pad
  {
    const f16* a1b = c1buf + rowA * HH + kq * 256 + akoff;  // buf0 = c_510
    const f16* a2b = c2buf + rowA * HH + kq * 256 + akoff;
    f32x4 oaH[2], oaL[2];
    #pragma unroll
    for (int mr = 0; mr < 2; ++mr) {
      oaH[mr] = (f32x4){0.f, 0.f, 0.f, 0.f};
      oaL[mr] = (f32x4){0.f, 0.f, 0.f, 0.f};
    }
    #pragma unroll
    for (int kc = 0; kc < 8; ++kc) {
      size_t f = (((size_t)slice * 4 + kq) * 2 + nh) * 8 + kc;
      half8 bw = *(const half8*)(Wo + (f * 64 + lane) * 8);
      #pragma unroll
      for (int mr = 0; mr < 2; ++mr) {
        half8 a1 = *(const half8*)(a1b + mr * 16 * HH + kc * 32);
        half8 a2 = *(const half8*)(a2b + mr * 16 * HH + kc * 32);
        oaH[mr] = __builtin_amdgcn_mfma_f32_16x16x32_f16(a1, bw, oaH[mr], 0, 0, 0);
        oaL[mr] = __builtin_amdgcn_mfma_f32_16x16x32_f16(a2, bw, oaL[mr], 0, 0, 0);
      }
    }
    f32x4 oa[2];
    #pragma unroll
    for (int mr = 0; mr < 2; ++mr)
      #pragma unroll
      for (int r = 0; r < 4; ++r)
        oa[mr][r] = fmaf(oaL[mr][r], LOINV, oaH[mr][r]);
    if (kq != 0) {
      #pragma unroll
      for (int mr = 0; mr < 2; ++mr)
        Rs[(((nh * 3 + (kq - 1)) * 2 + mr) * 2 + 0) * 64 + lane] = oa[mr];
    }
    __syncthreads();
    if (kq == 0) {
      #pragma unroll
      for (int q = 0; q < 3; ++q)
        #pragma unroll
        for (int mr = 0; mr < 2; ++mr)
          oa[mr] += Rs[(((nh * 3 + q) * 2 + mr) * 2 + 0) * 64 + lane];
      const int col = lane & 15;
      const float* cf1 = cfbuf + (size_t)(BB * HH);  // buf1 = c_511
      const int jj = j0 + nh * 16 + col;
      #pragma unroll
      for (int mr = 0; mr < 2; ++mr) {
        const int rbase = dom * 32 + mr * 16 + ((lane >> 4) << 2);
        #pragma unroll
        for (int r = 0; r < 4; ++r) {
          int b = rbase + r;
          unsigned vv = xv[b * SS + 510];
          float o = 1.f / (1.f + expf(-(oa[mr][r] + Go[vv * 1024 + jj])));
          float cn = cf1[b * HH + jj];
          float pd = vv ? 1.f : 0.f;
          hbuf[b * HH + jj] = tanhf(cn) * o * pd;
        }
      }
    }
  }
}

__global__ void k_proj(const float* __restrict__ hbuf, const float* __restrict__ w_ph,
                       const float* __restrict__ b_p, float* __restrict__ pbuf) {
  int wid = (blockIdx.x << 2) | (threadIdx.x >> 6);
  int lane = threadIdx.x & 63;
  const float* hrow = hbuf + (size_t)wid * HH;
  float s[NC];
  #pragma unroll
  for (int j = 0; j < NC; ++j) s[j] = 0.f;
  for (int m = 0; m < 16; ++m) {
    int k = m * 64 + lane;
    float hv = hrow[k];
    const float* wp = w_ph + k * NC;
    #pragma unroll
    for (int j = 0; j < NC; ++j) s[j] = fmaf(hv, wp[j], s[j]);
  }
  #pragma unroll
  for (int j = 0; j < NC; ++j) {
    float vv = s[j];
    for (int off = 32; off > 0; off >>= 1) vv += __shfl_down(vv, off);
    if (lane == 0) pbuf[wid * NC + j] = vv + b_p[j];
  }
}

__global__ void k_softmax(const float* __restrict__ pbuf, float* __restrict__ out) {
  __shared__ float ps[BB][NC];
  __shared__ float lse[NC];
  int b = threadIdx.x;
  #pragma unroll
  for (int j = 0; j < NC; ++j) ps[b][j] = pbuf[b * NC + j];
  __syncthreads();
  if (b < NC) {
    float m = -1e30f;
    for (int i = 0; i < BB; ++i) m = fmaxf(m, ps[i][b]);
    float sum = 0.f;
    for (int i = 0; i < BB; ++i) sum += expf(ps[i][b] - m);
    lse[b] = m + logf(sum);
  }
  __syncthreads();
  #pragma unroll
  for (int j = 0; j < NC; ++j) out[b * NC + j] = ps[b][j] - lse[j];
}

extern "C" void kernel_launch(void* const* d_in, const int* in_sizes, int n_in,
                              void* d_out, int out_size, void* d_ws, size_t ws_size,
                              hipStream_t stream) {
  const int*   x    = (const int*)d_in[0];
  const float* emb  = (const float*)d_in[1];
  const float* w_cx = (const float*)d_in[2];
  const float* b_c  = (const float*)d_in[3];
  const float* w_ix = (const float*)d_in[4];
  const float* w_ih = (const float*)d_in[5];
  const float* b_i  = (const float*)d_in[6];
  const float* w_fx = (const float*)d_in[7];
  const float* w_fh = (const float*)d_in[8];
  const float* b_f  = (const float*)d_in[9];
  const float* w_ox = (const float*)d_in[10];
  const float* w_oh = (const float*)d_in[11];
  const float* b_o  = (const float*)d_in[12];
  const float* w_ph = (const float*)d_in[13];
  const float* b_p  = (const float*)d_in[14];

  char* ws = (char*)d_ws;
  f16* W1  = (f16*)(ws + W1_OFF);
  f16* W2  = (f16*)(ws + W2_OFF);
  f16* W3  = (f16*)(ws + W3_OFF);
  f16* Wo  = (f16*)(ws + WO_OFF);
  float* Gif = (float*)(ws + GIF_OFF);
  float* Go  = (float*)(ws + GO_OFF);
  float* Cand = (float*)(ws + CAND_OFF);
  unsigned char* xv = (unsigned char*)(ws + XV_OFF);
  f16* c1buf = (f16*)(ws + C1_OFF);
  f16* c2buf = (f16*)(ws + C2_OFF);
  f16* c3buf = (f16*)(ws + C3_OFF);
  float* cfbuf = (float*)(ws + CF_OFF);
  float* hbuf = (float*)(ws + HBUF_OFF);
  float* pbuf = (float*)(ws + PBUF_OFF);
  unsigned* bar = (unsigned*)(ws + BAR_OFF);

  hipFuncSetAttribute((const void*)k_scan,
                      hipFuncAttributeMaxDynamicSharedMemorySize, SMEM_BYTES);

  hipMemsetAsync(c1buf, 0, (size_t)BB * HH * 2, stream);   // c_0 splits buf0 = 0
  hipMemsetAsync(c2buf, 0, (size_t)BB * HH * 2, stream);
  hipMemsetAsync(c3buf, 0, (size_t)BB * HH * 2, stream);
  hipMemsetAsync(cfbuf, 0, (size_t)BB * HH * 4, stream);   // c_0 fp32 buf0 = 0
  hipMemsetAsync(bar, 0, 4096, stream);

  k_xv<<<dim3((BB * SS + 255) / 256), dim3(256), 0, stream>>>(x, xv);
  k_tables<<<dim3(48), dim3(256), 0, stream>>>(emb, w_ix, w_fx, w_ox, w_cx,
                                               b_i, b_f, b_o, b_c, Gif, Go, Cand);
  k_fragw<<<dim3(1024), dim3(256), 0, stream>>>(w_ih, w_fh, W1, W2, W3);
  k_frago<<<dim3(512), dim3(256), 0, stream>>>(w_oh, Wo);
  k_scan<<<dim3(256), dim3(512), SMEM_BYTES, stream>>>(W1, W2, W3, Wo, Gif, Go, Cand,
                                                       xv, c1buf, c2buf, c3buf, cfbuf,
                                                       hbuf, bar);
  k_proj<<<dim3(64), dim3(256), 0, stream>>>(hbuf, w_ph, b_p, pbuf);
  k_softmax<<<dim3(1), dim3(256), 0, stream>>>(pbuf, (float*)d_out);
}

// Round 9
// 9979.426 us; speedup vs baseline: 1.7699x; 1.7699x over previous
//
#include <hip/hip_runtime.h>
#include <math.h>

#define BB 256
#define SS 512
#define TT 511
#define HH 1024
#define EE 512
#define NC 10

typedef _Float16 f16;
typedef __attribute__((ext_vector_type(8))) _Float16 half8;
typedef __attribute__((ext_vector_type(4))) float f32x4;

#define LOSCALE 2048.0f
#define LOINV   (1.0f / 2048.0f)
#define LOINV2  (1.0f / (2048.0f * 2048.0f))

// workspace offsets (bytes); total ~18.9 MB (ws held >= 21 MB in R8)
#define W1_OFF    0u          // f16 W1 frags [4096][64][8]   4 MB
#define W2_OFF    4194304u    // f16 W2 frags (x2048)         4 MB
#define W3_OFF    8388608u    // f16 W3 frags (x2048^2)       4 MB
#define WO_OFF    12582912u   // f16 W_oh frags [2048][64][8] 2 MB
#define GIF_OFF   14680064u   // f32 [3][2048] gx tables i,f (f64-computed)
#define GO_OFF    14704640u   // f32 [3][1024] gx table o
#define CAND_OFF  14716928u   // f32 [3][1024] sigmoid(gx_c)
#define C1_OFF    14729216u   // f16 [2][256][1024] c split 1
#define C2_OFF    15777792u   // f16 [2][256][1024] c split 2 (x2048)
#define C3_OFF    16826368u   // f16 [2][256][1024] c split 3 (x2048^2)
#define HBUF_OFF  17874944u   // f32 [256][1024]
#define PBUF_OFF  18923520u   // f32 [256][10]
#define BAR_OFF   18933760u   // 8 domains * 256B monotonic counters

// LDS: W2 128K | Rs 24K | xvp 4K | Gif 768 | Cand 384 | Go 384 = 161280
#define SMEM_BYTES 161280

// write-through (sc0 sc1) u16 store: lands at L3 coherence point, no dirty L2.
__device__ __forceinline__ void st16(f16* p, f16 v) {
  union { f16 h; unsigned short s; } u; u.h = v;
  unsigned w = u.s;
  asm volatile("global_store_short %0, %1, off sc0 sc1" :: "v"(p), "v"(w) : "memory");
}

// gx tables in DOUBLE precision (rounded once to f32)
__global__ void k_tables(const float* __restrict__ emb,
                         const float* __restrict__ w_ix, const float* __restrict__ w_fx,
                         const float* __restrict__ w_ox, const float* __restrict__ w_cx,
                         const float* __restrict__ b_i, const float* __restrict__ b_f,
                         const float* __restrict__ b_o, const float* __restrict__ b_c,
                         float* __restrict__ Gif, float* __restrict__ Go,
                         float* __restrict__ Cand) {
  int idx = blockIdx.x * 256 + threadIdx.x;
  if (idx >= 3 * 4096) return;
  int v = idx >> 12, g = idx & 4095;
  const float* ev = emb + v * EE;
  const float* W; float bias; float* dst; bool sig = false; int j;
  if (g < 1024)      { j = g;        W = w_ix; bias = b_i[j]; dst = Gif + v * 2048 + j; }
  else if (g < 2048) { j = g - 1024; W = w_fx; bias = b_f[j]; dst = Gif + v * 2048 + 1024 + j; }
  else if (g < 3072) { j = g - 2048; W = w_ox; bias = b_o[j]; dst = Go + v * 1024 + j; }
  else               { j = g - 3072; W = w_cx; bias = b_c[j]; dst = Cand + v * 1024 + j; sig = true; }
  double s = (double)bias;
  for (int e = 0; e < EE; ++e) s = fma((double)ev[e], (double)W[e * HH + j], s);
  if (sig) s = 1.0 / (1.0 + exp(-s));
  *dst = (float)s;
}

// W triple-split frags (exact: 11+11+11 bits >= fp32 24-bit mantissa)
// frag f = (((slice*4+kq)*2+nh)*2+nn)*8+kc ; element (f*64+lane)*8+e
__global__ void k_fragw(const float* __restrict__ w_ih, const float* __restrict__ w_fh,
                        f16* __restrict__ d1, f16* __restrict__ d2, f16* __restrict__ d3) {
  int idx = blockIdx.x * 256 + threadIdx.x;
  if (idx >= 262144) return;
  int l = idx & 63;
  int kc = (idx >> 6) & 7, nn = (idx >> 9) & 1, nh = (idx >> 10) & 1,
      kq = (idx >> 11) & 3, slice = idx >> 13;
  int col = l & 15;
  int jj = slice * 32 + nh * 16 + nn * 8 + (col & 7);
  const float* W = (col < 8) ? w_ih : w_fh;
  int k0 = kq * 256 + kc * 32 + ((l >> 4) << 3);
  half8 o1, o2, o3;
  #pragma unroll
  for (int e = 0; e < 8; ++e) {
    float w = W[(k0 + e) * HH + jj];
    f16 h1 = (f16)w;
    float r1 = (w - (float)h1) * LOSCALE;
    f16 h2 = (f16)r1;
    f16 h3 = (f16)((r1 - (float)h2) * LOSCALE);
    o1[e] = h1; o2[e] = h2; o3[e] = h3;
  }
  size_t off = (size_t)idx * 8;
  *(half8*)(d1 + off) = o1;
  *(half8*)(d2 + off) = o2;
  *(half8*)(d3 + off) = o3;
}

// W_oh single-f16 frags: f = ((slice*4+kq)*2+nh)*8+kc ; jj = slice*32+nh*16+col
__global__ void k_frago(const float* __restrict__ w_oh, f16* __restrict__ dst) {
  int idx = blockIdx.x * 256 + threadIdx.x;
  if (idx >= 131072) return;
  int l = idx & 63;
  int kc = (idx >> 6) & 7, nh = (idx >> 9) & 1, kq = (idx >> 10) & 3, slice = idx >> 12;
  int col = l & 15;
  int jj = slice * 32 + nh * 16 + col;
  int k0 = kq * 256 + kc * 32 + ((l >> 4) << 3);
  half8 out;
  #pragma unroll
  for (int e = 0; e < 8; ++e) out[e] = (f16)w_oh[(k0 + e) * HH + jj];
  *(half8*)(dst + (size_t)idx * 8) = out;
}

// Cheap domain barrier: c stores are write-through (sc0 sc1) and drained by the
// vmcnt(0) each wave performs at __syncthreads -> data is at L3 before arrive.
// Monotonic counter, relaxed agent atomics (no wbl2!), single buffer_inv acquire.
__device__ __forceinline__ void domain_barrier(unsigned* cnt, unsigned& mygen) {
  __syncthreads();   // each wave drains vmcnt before s_barrier -> stores visible at L3
  if (threadIdx.x == 0) {
    asm volatile("s_waitcnt vmcnt(0)" ::: "memory");
    mygen += 1u;
    __hip_atomic_fetch_add(cnt, 1u, __ATOMIC_RELAXED, __HIP_MEMORY_SCOPE_AGENT);
    unsigned target = 32u * mygen;
    while (__hip_atomic_load(cnt, __ATOMIC_RELAXED, __HIP_MEMORY_SCOPE_AGENT) < target) {
      __builtin_amdgcn_s_sleep(1);
    }
    __builtin_amdgcn_fence(__ATOMIC_ACQUIRE, "agent");  // buffer_inv sc1: L2 refill from L3
  }
  __syncthreads();
}

// persistent scan: 256 WGs x 512 thr (8 waves), 1 WG/CU (LDS 157.5K+ forces it).
// waves: w = nh*4 + kq. gh = c1W1 + (c2W1+c1W2)*2^-11 + (c3W1+c2W2+c1W3)*2^-22.
// c carried EXACTLY as triple f16 split (reconstruction is bit-exact fp32).
__global__ __launch_bounds__(512, 2) void k_scan(
    const f16* __restrict__ W1g, const f16* __restrict__ W2g, const f16* __restrict__ W3g,
    const f16* __restrict__ Wo,
    const float* __restrict__ Gif, const float* __restrict__ Go,
    const float* __restrict__ Cand, const int* __restrict__ x,
    f16* c1buf, f16* c2buf, f16* c3buf,
    float* __restrict__ hbuf, unsigned* bar) {
  extern __shared__ char smem[];
  f16*   W2s  = (f16*)smem;                              // 128 KB
  f32x4* Rs   = (f32x4*)(smem + 131072);                 // 24 KB
  unsigned char* xvpS = (unsigned char*)(smem + 155648); // 4 KB: [32 rows][128] 2-bit packed
  float* GifS = (float*)(smem + 159744);                 // [3][2][32]
  float* CandS = (float*)(smem + 160512);                // [3][32]
  float* GoS  = (float*)(smem + 160896);                 // [3][32]

  const int blk = blockIdx.x;
  const int dom = blk & 7;
  const int slice = blk >> 3;
  const int j0 = slice << 5;
  const int tid = threadIdx.x;
  const int lane = tid & 63;
  const int w = tid >> 6;
  const int kq = w & 3;
  const int nh = w >> 2;
  const int akoff = ((lane >> 4) << 3);
  const int rowA = dom * 32 + (lane & 15);   // A-row for mr=0; +16 for mr=1

  // --- init stashes ---
  {
    const half8* gsrc = (const half8*)(W2g + (size_t)slice * 65536);
    half8* ldst = (half8*)W2s;
    for (int i = tid; i < 8192; i += 512) ldst[i] = gsrc[i];
    for (int i = tid; i < 4096; i += 512) {              // pack x to 2 bits
      int row = i >> 7, tb = i & 127;
      const int* xp = x + (size_t)(dom * 32 + row) * SS + tb * 4;
      unsigned byte = (unsigned)(xp[0] & 3) | ((unsigned)(xp[1] & 3) << 2) |
                      ((unsigned)(xp[2] & 3) << 4) | ((unsigned)(xp[3] & 3) << 6);
      xvpS[i] = (unsigned char)byte;
    }
    for (int i = tid; i < 192; i += 512) {               // GifS[v][gate][jl]
      int v = i >> 6, gate = (i >> 5) & 1, jl = i & 31;
      GifS[i] = Gif[v * 2048 + gate * 1024 + j0 + jl];
    }
    for (int i = tid; i < 96; i += 512) {                // CandS, GoS [v][jl]
      int v = i >> 5, jl = i & 31;
      CandS[i] = Cand[v * 1024 + j0 + jl];
      GoS[i]   = Go[v * 1024 + j0 + jl];
    }
  }

  // W1, W3 in registers: per wave (kq,nh): nn(2) x kc(8) frags each = 128 VGPR
  half8 B1[8][2], B3[8][2];
  #pragma unroll
  for (int nn = 0; nn < 2; ++nn) {
    #pragma unroll
    for (int kc = 0; kc < 8; ++kc) {
      size_t f = ((((size_t)slice * 4 + kq) * 2 + nh) * 2 + nn) * 8 + kc;
      B1[kc][nn] = *(const half8*)(W1g + (f * 64 + lane) * 8);
      B3[kc][nn] = *(const half8*)(W3g + (f * 64 + lane) * 8);
    }
  }
  __syncthreads();

  const f16* w2Base = W2s + (kq * 2 + nh) * 8192 + lane * 8;  // + nn*4096 + kc*512

  unsigned mygen = 0;
  unsigned* bcnt = bar + dom * 64;

  for (int t = 0; t < TT; ++t) {
    const int pin = t & 1, pout = pin ^ 1;
    const f16* a1b = c1buf + (size_t)pin * (BB * HH) + rowA * HH + kq * 256 + akoff;
    const f16* a2b = c2buf + (size_t)pin * (BB * HH) + rowA * HH + kq * 256 + akoff;
    const f16* a3b = c3buf + (size_t)pin * (BB * HH) + rowA * HH + kq * 256 + akoff;
    const f16* c1in = c1buf + (size_t)pin * (BB * HH);
    const f16* c2in = c2buf + (size_t)pin * (BB * HH);
    const f16* c3in = c3buf + (size_t)pin * (BB * HH);
    f16* c1out = c1buf + (size_t)pout * (BB * HH);
    f16* c2out = c2buf + (size_t)pout * (BB * HH);
    f16* c3out = c3buf + (size_t)pout * (BB * HH);

    f32x4 accA[2][2], accB[2][2], accC[2][2];   // [mr][nn]
    #pragma unroll
    for (int mr = 0; mr < 2; ++mr)
      #pragma unroll
      for (int nn = 0; nn < 2; ++nn) {
        accA[mr][nn] = (f32x4){0.f, 0.f, 0.f, 0.f};
        accB[mr][nn] = (f32x4){0.f, 0.f, 0.f, 0.f};
        accC[mr][nn] = (f32x4){0.f, 0.f, 0.f, 0.f};
      }
    #pragma unroll
    for (int kc = 0; kc < 8; ++kc) {
      half8 a1[2], a2[2], a3[2];
      #pragma unroll
      for (int mr = 0; mr < 2; ++mr) {
        a1[mr] = *(const half8*)(a1b + mr * 16 * HH + kc * 32);
        a2[mr] = *(const half8*)(a2b + mr * 16 * HH + kc * 32);
        a3[mr] = *(const half8*)(a3b + mr * 16 * HH + kc * 32);
      }
      #pragma unroll
      for (int nn = 0; nn < 2; ++nn) {
        half8 w2 = *(const half8*)(w2Base + nn * 4096 + kc * 512);
        #pragma unroll
        for (int mr = 0; mr < 2; ++mr) {
          accA[mr][nn] = __builtin_amdgcn_mfma_f32_16x16x32_f16(a1[mr], B1[kc][nn], accA[mr][nn], 0, 0, 0);
          accB[mr][nn] = __builtin_amdgcn_mfma_f32_16x16x32_f16(a2[mr], B1[kc][nn], accB[mr][nn], 0, 0, 0);
          accB[mr][nn] = __builtin_amdgcn_mfma_f32_16x16x32_f16(a1[mr], w2, accB[mr][nn], 0, 0, 0);
          accC[mr][nn] = __builtin_amdgcn_mfma_f32_16x16x32_f16(a3[mr], B1[kc][nn], accC[mr][nn], 0, 0, 0);
          accC[mr][nn] = __builtin_amdgcn_mfma_f32_16x16x32_f16(a2[mr], w2, accC[mr][nn], 0, 0, 0);
          accC[mr][nn] = __builtin_amdgcn_mfma_f32_16x16x32_f16(a1[mr], B3[kc][nn], accC[mr][nn], 0, 0, 0);
        }
      }
    }
    f32x4 gh[2][2];
    #pragma unroll
    for (int mr = 0; mr < 2; ++mr)
      #pragma unroll
      for (int nn = 0; nn < 2; ++nn)
        #pragma unroll
        for (int r = 0; r < 4; ++r)
          gh[mr][nn][r] = fmaf(accC[mr][nn][r], LOINV2,
                               fmaf(accB[mr][nn][r], LOINV, accA[mr][nn][r]));
    if (kq != 0) {
      #pragma unroll
      for (int mr = 0; mr < 2; ++mr)
        #pragma unroll
        for (int nn = 0; nn < 2; ++nn)
          Rs[(((nh * 3 + (kq - 1)) * 2 + mr) * 2 + nn) * 64 + lane] = gh[mr][nn];
    }
    __syncthreads();
    if (kq == 0) {
      #pragma unroll
      for (int q = 0; q < 3; ++q)
        #pragma unroll
        for (int mr = 0; mr < 2; ++mr)
          #pragma unroll
          for (int nn = 0; nn < 2; ++nn)
            gh[mr][nn] += Rs[(((nh * 3 + q) * 2 + mr) * 2 + nn) * 64 + lane];
      const int col = lane & 15;
      const bool isI = col < 8;
      const int jcol = col & 7;
      const int gsel = isI ? 0 : 1;
      const int tb = t >> 2, tsh = (t & 3) << 1;
      #pragma unroll
      for (int mr = 0; mr < 2; ++mr) {
        const int rloc0 = mr * 16 + ((lane >> 4) << 2);       // domain-local row base
        unsigned v[4];
        #pragma unroll
        for (int r = 0; r < 4; ++r)
          v[r] = (xvpS[(rloc0 + r) * 128 + tb] >> tsh) & 3u;
        #pragma unroll
        for (int nn = 0; nn < 2; ++nn) {
          const int jl = nh * 16 + nn * 8 + jcol;             // local col 0..31
          const int jj = j0 + jl;
          float sg[4];
          #pragma unroll
          for (int r = 0; r < 4; ++r) {
            float pre = gh[mr][nn][r] + GifS[(v[r] * 2 + gsel) * 32 + jl];
            sg[r] = 1.f / (1.f + expf(-pre));
          }
          float ot[4];
          #pragma unroll
          for (int r = 0; r < 4; ++r) ot[r] = __shfl_xor(sg[r], 8);
          const int rlo = isI ? 0 : 2;
          #pragma unroll
          for (int q = 0; q < 2; ++q) {
            int r = rlo + q;
            int b = dom * 32 + rloc0 + r;
            size_t off = (size_t)b * HH + jj;
            float iv = isI ? sg[r] : ot[r];
            float fv = isI ? ot[r] : sg[r];
            float cd = CandS[v[r] * 32 + jl];
            // exact fp32 c reconstruction from the triple split
            float co = (float)c1in[off] +
                       fmaf((float)c3in[off], LOINV2, (float)c2in[off] * LOINV);
            float cn = fmaf(cd, iv, co * fv);
            f16 h1 = (f16)cn;
            float r1 = (cn - (float)h1) * LOSCALE;
            f16 h2 = (f16)r1;
            f16 h3 = (f16)((r1 - (float)h2) * LOSCALE);
            st16(c1out + off, h1);   // write-through: visible at L3 after vmcnt drain
            st16(c2out + off, h2);
            st16(c3out + off, h3);
          }
        }
      }
    }
    domain_barrier(bcnt, mygen);
  }

  // ---- last step: o gate from c_510 (buf0, hi+mid), h = tanh(c_511)*o*pad
  {
    const f16* a1b = c1buf + rowA * HH + kq * 256 + akoff;  // buf0 = c_510
    const f16* a2b = c2buf + rowA * HH + kq * 256 + akoff;
    f32x4 oaH[2], oaL[2];
    #pragma unroll
    for (int mr = 0; mr < 2; ++mr) {
      oaH[mr] = (f32x4){0.f, 0.f, 0.f, 0.f};
      oaL[mr] = (f32x4){0.f, 0.f, 0.f, 0.f};
    }
    #pragma unroll
    for (int kc = 0; kc < 8; ++kc) {
      size_t f = (((size_t)slice * 4 + kq) * 2 + nh) * 8 + kc;
      half8 bw = *(const half8*)(Wo + (f * 64 + lane) * 8);
      #pragma unroll
      for (int mr = 0; mr < 2; ++mr) {
        half8 a1 = *(const half8*)(a1b + mr * 16 * HH + kc * 32);
        half8 a2 = *(const half8*)(a2b + mr * 16 * HH + kc * 32);
        oaH[mr] = __builtin_amdgcn_mfma_f32_16x16x32_f16(a1, bw, oaH[mr], 0, 0, 0);
        oaL[mr] = __builtin_amdgcn_mfma_f32_16x16x32_f16(a2, bw, oaL[mr], 0, 0, 0);
      }
    }
    f32x4 oa[2];
    #pragma unroll
    for (int mr = 0; mr < 2; ++mr)
      #pragma unroll
      for (int r = 0; r < 4; ++r)
        oa[mr][r] = fmaf(oaL[mr][r], LOINV, oaH[mr][r]);
    if (kq != 0) {
      #pragma unroll
      for (int mr = 0; mr < 2; ++mr)
        Rs[(((nh * 3 + (kq - 1)) * 2 + mr) * 2 + 0) * 64 + lane] = oa[mr];
    }
    __syncthreads();
    if (kq == 0) {
      #pragma unroll
      for (int q = 0; q < 3; ++q)
        #pragma unroll
        for (int mr = 0; mr < 2; ++mr)
          oa[mr] += Rs[(((nh * 3 + q) * 2 + mr) * 2 + 0) * 64 + lane];
      const int col = lane & 15;
      const f16* c1b1 = c1buf + (size_t)(BB * HH);  // buf1 = c_511
      const f16* c2b1 = c2buf + (size_t)(BB * HH);
      const f16* c3b1 = c3buf + (size_t)(BB * HH);
      const int jl = nh * 16 + col;
      const int jj = j0 + jl;
      #pragma unroll
      for (int mr = 0; mr < 2; ++mr) {
        const int rloc0 = mr * 16 + ((lane >> 4) << 2);
        #pragma unroll
        for (int r = 0; r < 4; ++r) {
          int b = dom * 32 + rloc0 + r;
          size_t off = (size_t)b * HH + jj;
          unsigned vv = (xvpS[(rloc0 + r) * 128 + 127] >> 4) & 3u;  // t = 510
          float o = 1.f / (1.f + expf(-(oa[mr][r] + GoS[vv * 32 + jl])));
          float cn = (float)c1b1[off] +
                     fmaf((float)c3b1[off], LOINV2, (float)c2b1[off] * LOINV);
          float pd = vv ? 1.f : 0.f;
          hbuf[off] = tanhf(cn) * o * pd;
        }
      }
    }
  }
}

__global__ void k_proj(const float* __restrict__ hbuf, const float* __restrict__ w_ph,
                       const float* __restrict__ b_p, float* __restrict__ pbuf) {
  int wid = (blockIdx.x << 2) | (threadIdx.x >> 6);
  int lane = threadIdx.x & 63;
  const float* hrow = hbuf + (size_t)wid * HH;
  float s[NC];
  #pragma unroll
  for (int j = 0; j < NC; ++j) s[j] = 0.f;
  for (int m = 0; m < 16; ++m) {
    int k = m * 64 + lane;
    float hv = hrow[k];
    const float* wp = w_ph + k * NC;
    #pragma unroll
    for (int j = 0; j < NC; ++j) s[j] = fmaf(hv, wp[j], s[j]);
  }
  #pragma unroll
  for (int j = 0; j < NC; ++j) {
    float vv = s[j];
    for (int off = 32; off > 0; off >>= 1) vv += __shfl_down(vv, off);
    if (lane == 0) pbuf[wid * NC + j] = vv + b_p[j];
  }
}

__global__ void k_softmax(const float* __restrict__ pbuf, float* __restrict__ out) {
  __shared__ float ps[BB][NC];
  __shared__ float lse[NC];
  int b = threadIdx.x;
  #pragma unroll
  for (int j = 0; j < NC; ++j) ps[b][j] = pbuf[b * NC + j];
  __syncthreads();
  if (b < NC) {
    float m = -1e30f;
    for (int i = 0; i < BB; ++i) m = fmaxf(m, ps[i][b]);
    float sum = 0.f;
    for (int i = 0; i < BB; ++i) sum += expf(ps[i][b] - m);
    lse[b] = m + logf(sum);
  }
  __syncthreads();
  #pragma unroll
  for (int j = 0; j < NC; ++j) out[b * NC + j] = ps[b][j] - lse[j];
}

extern "C" void kernel_launch(void* const* d_in, const int* in_sizes, int n_in,
                              void* d_out, int out_size, void* d_ws, size_t ws_size,
                              hipStream_t stream) {
  const int*   x    = (const int*)d_in[0];
  const float* emb  = (const float*)d_in[1];
  const float* w_cx = (const float*)d_in[2];
  const float* b_c  = (const float*)d_in[3];
  const float* w_ix = (const float*)d_in[4];
  const float* w_ih = (const float*)d_in[5];
  const float* b_i  = (const float*)d_in[6];
  const float* w_fx = (const float*)d_in[7];
  const float* w_fh = (const float*)d_in[8];
  const float* b_f  = (const float*)d_in[9];
  const float* w_ox = (const float*)d_in[10];
  const float* w_oh = (const float*)d_in[11];
  const float* b_o  = (const float*)d_in[12];
  const float* w_ph = (const float*)d_in[13];
  const float* b_p  = (const float*)d_in[14];

  char* ws = (char*)d_ws;
  f16* W1  = (f16*)(ws + W1_OFF);
  f16* W2  = (f16*)(ws + W2_OFF);
  f16* W3  = (f16*)(ws + W3_OFF);
  f16* Wo  = (f16*)(ws + WO_OFF);
  float* Gif = (float*)(ws + GIF_OFF);
  float* Go  = (float*)(ws + GO_OFF);
  float* Cand = (float*)(ws + CAND_OFF);
  f16* c1buf = (f16*)(ws + C1_OFF);
  f16* c2buf = (f16*)(ws + C2_OFF);
  f16* c3buf = (f16*)(ws + C3_OFF);
  float* hbuf = (float*)(ws + HBUF_OFF);
  float* pbuf = (float*)(ws + PBUF_OFF);
  unsigned* bar = (unsigned*)(ws + BAR_OFF);

  hipFuncSetAttribute((const void*)k_scan,
                      hipFuncAttributeMaxDynamicSharedMemorySize, SMEM_BYTES);

  hipMemsetAsync(c1buf, 0, (size_t)BB * HH * 2, stream);   // c_0 splits buf0 = 0
  hipMemsetAsync(c2buf, 0, (size_t)BB * HH * 2, stream);
  hipMemsetAsync(c3buf, 0, (size_t)BB * HH * 2, stream);
  hipMemsetAsync(bar, 0, 4096, stream);                    // monotonic counters

  k_tables<<<dim3(48), dim3(256), 0, stream>>>(emb, w_ix, w_fx, w_ox, w_cx,
                                               b_i, b_f, b_o, b_c, Gif, Go, Cand);
  k_fragw<<<dim3(1024), dim3(256), 0, stream>>>(w_ih, w_fh, W1, W2, W3);
  k_frago<<<dim3(512), dim3(256), 0, stream>>>(w_oh, Wo);
  k_scan<<<dim3(256), dim3(512), SMEM_BYTES, stream>>>(W1, W2, W3, Wo, Gif, Go, Cand,
                                                       x, c1buf, c2buf, c3buf,
                                                       hbuf, bar);
  k_proj<<<dim3(64), dim3(256), 0, stream>>>(hbuf, w_ph, b_p, pbuf);
  k_softmax<<<dim3(1), dim3(256), 0, stream>>>(pbuf, (float*)d_out);
}

// Round 11
// 8108.454 us; speedup vs baseline: 2.1783x; 1.2307x over previous
//
#include <hip/hip_runtime.h>
#include <math.h>

#define BB 256
#define SS 512
#define TT 511
#define HH 1024
#define EE 512
#define NC 10

typedef _Float16 f16;
typedef __attribute__((ext_vector_type(8))) _Float16 half8;
typedef __attribute__((ext_vector_type(4))) float f32x4;

#define LOSCALE 2048.0f
#define LOINV   (1.0f / 2048.0f)
#define LOINV2  (1.0f / (2048.0f * 2048.0f))

// workspace offsets (bytes)
#define W1_OFF    0u          // f16 W1 frags [4096][64][8]   4 MB
#define W2_OFF    4194304u    // f16 W2 frags (x2048)         4 MB
#define W3_OFF    8388608u    // f16 W3 frags (x2048^2)       4 MB
#define WO_OFF    12582912u   // f16 W_oh frags [2048][64][8] 2 MB
#define GIF_OFF   14680064u   // f32 [3][2048] gx tables i,f (f64-computed)
#define GO_OFF    14704640u   // f32 [3][1024] gx table o
#define CAND_OFF  14716928u   // f32 [3][1024] sigmoid(gx_c)
#define C1_OFF    14729216u   // f16 [2][256][1024] c split 1
#define C2_OFF    15777792u   // f16 [2][256][1024] c split 2 (x2048)
#define C3_OFF    16826368u   // f16 [2][256][1024] c split 3 (x2048^2)
#define HBUF_OFF  17874944u   // f32 [256][1024]
#define PBUF_OFF  18923520u   // f32 [256][10]
#define BAR_OFF   18933760u   // barrier region (4 KB, memset each launch)

// bar layout (unsigned indices): [0]=gcnt ; [16+x*16]=xcnt[x] ; [256+d*16]=dombar[d]

// LDS: W2 128K | Rs 24K | xvp 4K | Gif 768 | Cand 384 | Go 384 | shS 16 = 161296
#define SMEM_BYTES 161296

// system-scope write-through u16 store (fallback path for impure doms only)
__device__ __forceinline__ void st16(f16* p, f16 v) {
  union { f16 h; unsigned short s; } u; u.h = v;
  unsigned w = u.s;
  asm volatile("global_store_short %0, %1, off sc0 sc1" :: "v"(p), "v"(w) : "memory");
}

// gx tables in DOUBLE precision (rounded once to f32)
__global__ void k_tables(const float* __restrict__ emb,
                         const float* __restrict__ w_ix, const float* __restrict__ w_fx,
                         const float* __restrict__ w_ox, const float* __restrict__ w_cx,
                         const float* __restrict__ b_i, const float* __restrict__ b_f,
                         const float* __restrict__ b_o, const float* __restrict__ b_c,
                         float* __restrict__ Gif, float* __restrict__ Go,
                         float* __restrict__ Cand) {
  int idx = blockIdx.x * 256 + threadIdx.x;
  if (idx >= 3 * 4096) return;
  int v = idx >> 12, g = idx & 4095;
  const float* ev = emb + v * EE;
  const float* W; float bias; float* dst; bool sig = false; int j;
  if (g < 1024)      { j = g;        W = w_ix; bias = b_i[j]; dst = Gif + v * 2048 + j; }
  else if (g < 2048) { j = g - 1024; W = w_fx; bias = b_f[j]; dst = Gif + v * 2048 + 1024 + j; }
  else if (g < 3072) { j = g - 2048; W = w_ox; bias = b_o[j]; dst = Go + v * 1024 + j; }
  else               { j = g - 3072; W = w_cx; bias = b_c[j]; dst = Cand + v * 1024 + j; sig = true; }
  double s = (double)bias;
  for (int e = 0; e < EE; ++e) s = fma((double)ev[e], (double)W[e * HH + j], s);
  if (sig) s = 1.0 / (1.0 + exp(-s));
  *dst = (float)s;
}

// W triple-split frags (exact: 11+11+11 bits >= fp32 24-bit mantissa)
// frag f = (((slice*4+kq)*2+nh)*2+nn)*8+kc ; element (f*64+lane)*8+e
__global__ void k_fragw(const float* __restrict__ w_ih, const float* __restrict__ w_fh,
                        f16* __restrict__ d1, f16* __restrict__ d2, f16* __restrict__ d3) {
  int idx = blockIdx.x * 256 + threadIdx.x;
  if (idx >= 262144) return;
  int l = idx & 63;
  int kc = (idx >> 6) & 7, nn = (idx >> 9) & 1, nh = (idx >> 10) & 1,
      kq = (idx >> 11) & 3, slice = idx >> 13;
  int col = l & 15;
  int jj = slice * 32 + nh * 16 + nn * 8 + (col & 7);
  const float* W = (col < 8) ? w_ih : w_fh;
  int k0 = kq * 256 + kc * 32 + ((l >> 4) << 3);
  half8 o1, o2, o3;
  #pragma unroll
  for (int e = 0; e < 8; ++e) {
    float w = W[(k0 + e) * HH + jj];
    f16 h1 = (f16)w;
    float r1 = (w - (float)h1) * LOSCALE;
    f16 h2 = (f16)r1;
    f16 h3 = (f16)((r1 - (float)h2) * LOSCALE);
    o1[e] = h1; o2[e] = h2; o3[e] = h3;
  }
  size_t off = (size_t)idx * 8;
  *(half8*)(d1 + off) = o1;
  *(half8*)(d2 + off) = o2;
  *(half8*)(d3 + off) = o3;
}

// W_oh single-f16 frags: f = ((slice*4+kq)*2+nh)*8+kc ; jj = slice*32+nh*16+col
__global__ void k_frago(const float* __restrict__ w_oh, f16* __restrict__ dst) {
  int idx = blockIdx.x * 256 + threadIdx.x;
  if (idx >= 131072) return;
  int l = idx & 63;
  int kc = (idx >> 6) & 7, nh = (idx >> 9) & 1, kq = (idx >> 10) & 3, slice = idx >> 12;
  int col = l & 15;
  int jj = slice * 32 + nh * 16 + col;
  int k0 = kq * 256 + kc * 32 + ((l >> 4) << 3);
  half8 out;
  #pragma unroll
  for (int e = 0; e < 8; ++e) out[e] = (f16)w_oh[(k0 + e) * HH + jj];
  *(half8*)(dst + (size_t)idx * 8) = out;
}

// Domain barrier: monotonic counter, PROVEN R9 builtins (agent atomics at L3;
// loads emit sc1 -> always fresh, no L1-stale livelock). Exactly 32 members per
// dom BY CONSTRUCTION (rank-based assignment) -> can never starve.
// Acquire: pure dom -> L1-only buffer_inv (c is dirty in the shared XCD L2);
//          impure   -> agent acquire fence (L1+L2 inv; c was written through).
__device__ __forceinline__ void domain_barrier(unsigned* cnt, unsigned& mygen, bool pure) {
  __syncthreads();   // compiler drains vmcnt before s_barrier: all c stores ACKed
  if (threadIdx.x == 0) {
    mygen += 1u;
    __hip_atomic_fetch_add(cnt, 1u, __ATOMIC_RELAXED, __HIP_MEMORY_SCOPE_AGENT);
    const unsigned target = 32u * mygen;
    while (__hip_atomic_load(cnt, __ATOMIC_RELAXED, __HIP_MEMORY_SCOPE_AGENT) < target) {
      __builtin_amdgcn_s_sleep(1);
    }
    if (pure) {
      asm volatile("buffer_inv" ::: "memory");            // L1 invalidate only
    } else {
      __builtin_amdgcn_fence(__ATOMIC_ACQUIRE, "agent");  // L1+L2 invalidate
    }
  }
  __syncthreads();
}

// persistent scan: 256 WGs x 512 thr, 1 WG/CU (LDS-forced -> all co-resident).
// Self-organized: rank = XCD-sorted global index; dom=rank>>5 (rows), slice=rank&31
// (cols). Pure dom (fits one XCD): c stays dirty in XCD-local L2. Impure: R9 path.
// gh = c1W1 + (c2W1+c1W2)*2^-11 + (c3W1+c2W2+c1W3)*2^-22 ; c exact (triple f16).
__global__ __launch_bounds__(512, 2) void k_scan(
    const f16* __restrict__ W1g, const f16* __restrict__ W2g, const f16* __restrict__ W3g,
    const f16* __restrict__ Wo,
    const float* __restrict__ Gif, const float* __restrict__ Go,
    const float* __restrict__ Cand, const int* __restrict__ x,
    f16* c1buf, f16* c2buf, f16* c3buf,
    float* __restrict__ hbuf, unsigned* bar) {
  extern __shared__ char smem[];
  f16*   W2s  = (f16*)smem;                              // 128 KB
  f32x4* Rs   = (f32x4*)(smem + 131072);                 // 24 KB
  unsigned char* xvpS = (unsigned char*)(smem + 155648); // 4 KB: [32 rows][128] 2-bit packed
  float* GifS = (float*)(smem + 159744);                 // [3][2][32]
  float* CandS = (float*)(smem + 160512);                // [3][32]
  float* GoS  = (float*)(smem + 160896);                 // [3][32]
  unsigned* shS = (unsigned*)(smem + 161280);            // {dom, slice, pure}

  const int tid = threadIdx.x;
  const int lane = tid & 63;
  const int w = tid >> 6;
  const int kq = w & 3;
  const int nh = w >> 2;
  const int akoff = ((lane >> 4) << 3);

  // --- self-organize: per-XCD slot claim -> global barrier -> XCD-sorted rank ---
  if (tid == 0) {
    unsigned xcd;
    asm volatile("s_getreg_b32 %0, hwreg(HW_REG_XCC_ID)" : "=s"(xcd));
    xcd &= 7u;
    unsigned slot = __hip_atomic_fetch_add(bar + 16 + xcd * 16, 1u,
                                           __ATOMIC_RELAXED, __HIP_MEMORY_SCOPE_AGENT);
    __hip_atomic_fetch_add(bar, 1u, __ATOMIC_RELEASE, __HIP_MEMORY_SCOPE_AGENT);
    while (__hip_atomic_load(bar, __ATOMIC_ACQUIRE, __HIP_MEMORY_SCOPE_AGENT) < 256u) {
      __builtin_amdgcn_s_sleep(1);
    }
    unsigned mybase = 0, mycnt = 0;
    for (int xx = 0; xx < 8; ++xx) {
      unsigned c = __hip_atomic_load(bar + 16 + xx * 16,
                                     __ATOMIC_RELAXED, __HIP_MEMORY_SCOPE_AGENT);
      if (xx < (int)xcd) mybase += c;
      if (xx == (int)xcd) mycnt = c;
    }
    unsigned rank = mybase + slot;
    unsigned dm = rank >> 5, sl = rank & 31u;
    unsigned dlo = dm << 5, dhi = dlo + 32u;
    unsigned pure = (mybase <= dlo && dhi <= mybase + mycnt) ? 1u : 0u;
    shS[0] = dm; shS[1] = sl; shS[2] = pure;
  }
  __syncthreads();
  const int dom = (int)shS[0];
  const int slice = (int)shS[1];
  const bool pure = shS[2] != 0u;
  const int j0 = slice << 5;
  const int rowA = dom * 32 + (lane & 15);   // A-row for mr=0; +16 for mr=1

  // --- init stashes ---
  {
    const half8* gsrc = (const half8*)(W2g + (size_t)slice * 65536);
    half8* ldst = (half8*)W2s;
    for (int i = tid; i < 8192; i += 512) ldst[i] = gsrc[i];
    for (int i = tid; i < 4096; i += 512) {              // pack x to 2 bits
      int row = i >> 7, tb = i & 127;
      const int* xp = x + (size_t)(dom * 32 + row) * SS + tb * 4;
      unsigned byte = (unsigned)(xp[0] & 3) | ((unsigned)(xp[1] & 3) << 2) |
                      ((unsigned)(xp[2] & 3) << 4) | ((unsigned)(xp[3] & 3) << 6);
      xvpS[i] = (unsigned char)byte;
    }
    for (int i = tid; i < 192; i += 512) {               // GifS[v][gate][jl]
      int v = i >> 6, gate = (i >> 5) & 1, jl = i & 31;
      GifS[i] = Gif[v * 2048 + gate * 1024 + j0 + jl];
    }
    for (int i = tid; i < 96; i += 512) {                // CandS, GoS [v][jl]
      int v = i >> 5, jl = i & 31;
      CandS[i] = Cand[v * 1024 + j0 + jl];
      GoS[i]   = Go[v * 1024 + j0 + jl];
    }
  }

  // W1, W3 in registers: per wave (kq,nh): nn(2) x kc(8) frags each
  half8 B1[8][2], B3[8][2];
  #pragma unroll
  for (int nn = 0; nn < 2; ++nn) {
    #pragma unroll
    for (int kc = 0; kc < 8; ++kc) {
      size_t f = ((((size_t)slice * 4 + kq) * 2 + nh) * 2 + nn) * 8 + kc;
      B1[kc][nn] = *(const half8*)(W1g + (f * 64 + lane) * 8);
      B3[kc][nn] = *(const half8*)(W3g + (f * 64 + lane) * 8);
    }
  }
  __syncthreads();

  const f16* w2Base = W2s + (kq * 2 + nh) * 8192 + lane * 8;  // + nn*4096 + kc*512

  unsigned mygen = 0;
  unsigned* bcnt = bar + 256 + dom * 16;

  for (int t = 0; t < TT; ++t) {
    const int pin = t & 1, pout = pin ^ 1;
    const f16* a1b = c1buf + (size_t)pin * (BB * HH) + rowA * HH + kq * 256 + akoff;
    const f16* a2b = c2buf + (size_t)pin * (BB * HH) + rowA * HH + kq * 256 + akoff;
    const f16* a3b = c3buf + (size_t)pin * (BB * HH) + rowA * HH + kq * 256 + akoff;
    const f16* c1in = c1buf + (size_t)pin * (BB * HH);
    const f16* c2in = c2buf + (size_t)pin * (BB * HH);
    const f16* c3in = c3buf + (size_t)pin * (BB * HH);
    f16* c1out = c1buf + (size_t)pout * (BB * HH);
    f16* c2out = c2buf + (size_t)pout * (BB * HH);
    f16* c3out = c3buf + (size_t)pout * (BB * HH);

    f32x4 accA[2][2], accB[2][2], accC[2][2];   // [mr][nn]
    #pragma unroll
    for (int mr = 0; mr < 2; ++mr)
      #pragma unroll
      for (int nn = 0; nn < 2; ++nn) {
        accA[mr][nn] = (f32x4){0.f, 0.f, 0.f, 0.f};
        accB[mr][nn] = (f32x4){0.f, 0.f, 0.f, 0.f};
        accC[mr][nn] = (f32x4){0.f, 0.f, 0.f, 0.f};
      }
    #pragma unroll
    for (int kc = 0; kc < 8; ++kc) {
      half8 a1[2], a2[2], a3[2];
      #pragma unroll
      for (int mr = 0; mr < 2; ++mr) {
        a1[mr] = *(const half8*)(a1b + mr * 16 * HH + kc * 32);
        a2[mr] = *(const half8*)(a2b + mr * 16 * HH + kc * 32);
        a3[mr] = *(const half8*)(a3b + mr * 16 * HH + kc * 32);
      }
      #pragma unroll
      for (int nn = 0; nn < 2; ++nn) {
        half8 w2 = *(const half8*)(w2Base + nn * 4096 + kc * 512);
        #pragma unroll
        for (int mr = 0; mr < 2; ++mr) {
          accA[mr][nn] = __builtin_amdgcn_mfma_f32_16x16x32_f16(a1[mr], B1[kc][nn], accA[mr][nn], 0, 0, 0);
          accB[mr][nn] = __builtin_amdgcn_mfma_f32_16x16x32_f16(a2[mr], B1[kc][nn], accB[mr][nn], 0, 0, 0);
          accB[mr][nn] = __builtin_amdgcn_mfma_f32_16x16x32_f16(a1[mr], w2, accB[mr][nn], 0, 0, 0);
          accC[mr][nn] = __builtin_amdgcn_mfma_f32_16x16x32_f16(a3[mr], B1[kc][nn], accC[mr][nn], 0, 0, 0);
          accC[mr][nn] = __builtin_amdgcn_mfma_f32_16x16x32_f16(a2[mr], w2, accC[mr][nn], 0, 0, 0);
          accC[mr][nn] = __builtin_amdgcn_mfma_f32_16x16x32_f16(a1[mr], B3[kc][nn], accC[mr][nn], 0, 0, 0);
        }
      }
    }
    f32x4 gh[2][2];
    #pragma unroll
    for (int mr = 0; mr < 2; ++mr)
      #pragma unroll
      for (int nn = 0; nn < 2; ++nn)
        #pragma unroll
        for (int r = 0; r < 4; ++r)
          gh[mr][nn][r] = fmaf(accC[mr][nn][r], LOINV2,
                               fmaf(accB[mr][nn][r], LOINV, accA[mr][nn][r]));
    if (kq != 0) {
      #pragma unroll
      for (int mr = 0; mr < 2; ++mr)
        #pragma unroll
        for (int nn = 0; nn < 2; ++nn)
          Rs[(((nh * 3 + (kq - 1)) * 2 + mr) * 2 + nn) * 64 + lane] = gh[mr][nn];
    }
    __syncthreads();
    if (kq == 0) {
      #pragma unroll
      for (int q = 0; q < 3; ++q)
        #pragma unroll
        for (int mr = 0; mr < 2; ++mr)
          #pragma unroll
          for (int nn = 0; nn < 2; ++nn)
            gh[mr][nn] += Rs[(((nh * 3 + q) * 2 + mr) * 2 + nn) * 64 + lane];
      const int col = lane & 15;
      const bool isI = col < 8;
      const int jcol = col & 7;
      const int gsel = isI ? 0 : 1;
      const int tb = t >> 2, tsh = (t & 3) << 1;
      #pragma unroll
      for (int mr = 0; mr < 2; ++mr) {
        const int rloc0 = mr * 16 + ((lane >> 4) << 2);       // domain-local row base
        unsigned v[4];
        #pragma unroll
        for (int r = 0; r < 4; ++r)
          v[r] = (xvpS[(rloc0 + r) * 128 + tb] >> tsh) & 3u;
        #pragma unroll
        for (int nn = 0; nn < 2; ++nn) {
          const int jl = nh * 16 + nn * 8 + jcol;             // local col 0..31
          const int jj = j0 + jl;
          float sg[4];
          #pragma unroll
          for (int r = 0; r < 4; ++r) {
            float pre = gh[mr][nn][r] + GifS[(v[r] * 2 + gsel) * 32 + jl];
            sg[r] = 1.f / (1.f + expf(-pre));
          }
          float ot[4];
          #pragma unroll
          for (int r = 0; r < 4; ++r) ot[r] = __shfl_xor(sg[r], 8);
          const int rlo = isI ? 0 : 2;
          #pragma unroll
          for (int q = 0; q < 2; ++q) {
            int r = rlo + q;
            int b = dom * 32 + rloc0 + r;
            size_t off = (size_t)b * HH + jj;
            float iv = isI ? sg[r] : ot[r];
            float fv = isI ? ot[r] : sg[r];
            float cd = CandS[v[r] * 32 + jl];
            // exact fp32 c reconstruction from the triple split
            float co = (float)c1in[off] +
                       fmaf((float)c3in[off], LOINV2, (float)c2in[off] * LOINV);
            float cn = fmaf(cd, iv, co * fv);
            f16 h1 = (f16)cn;
            float r1 = (cn - (float)h1) * LOSCALE;
            f16 h2 = (f16)r1;
            f16 h3 = (f16)((r1 - (float)h2) * LOSCALE);
            if (pure) {
              c1out[off] = h1;        // plain stores: dirty in XCD-local L2
              c2out[off] = h2;
              c3out[off] = h3;
            } else {
              st16(c1out + off, h1);  // fallback: write-through to coherence point
              st16(c2out + off, h2);
              st16(c3out + off, h3);
            }
          }
        }
      }
    }
    domain_barrier(bcnt, mygen, pure);
  }

  // ---- last step: o gate from c_510 (buf0, hi+mid), h = tanh(c_511)*o*pad
  {
    const f16* a1b = c1buf + rowA * HH + kq * 256 + akoff;  // buf0 = c_510
    const f16* a2b = c2buf + rowA * HH + kq * 256 + akoff;
    f32x4 oaH[2], oaL[2];
    #pragma unroll
    for (int mr = 0; mr < 2; ++mr) {
      oaH[mr] = (f32x4){0.f, 0.f, 0.f, 0.f};
      oaL[mr] = (f32x4){0.f, 0.f, 0.f, 0.f};
    }
    #pragma unroll
    for (int kc = 0; kc < 8; ++kc) {
      size_t f = (((size_t)slice * 4 + kq) * 2 + nh) * 8 + kc;
      half8 bw = *(const half8*)(Wo + (f * 64 + lane) * 8);
      #pragma unroll
      for (int mr = 0; mr < 2; ++mr) {
        half8 a1 = *(const half8*)(a1b + mr * 16 * HH + kc * 32);
        half8 a2 = *(const half8*)(a2b + mr * 16 * HH + kc * 32);
        oaH[mr] = __builtin_amdgcn_mfma_f32_16x16x32_f16(a1, bw, oaH[mr], 0, 0, 0);
        oaL[mr] = __builtin_amdgcn_mfma_f32_16x16x32_f16(a2, bw, oaL[mr], 0, 0, 0);
      }
    }
    f32x4 oa[2];
    #pragma unroll
    for (int mr = 0; mr < 2; ++mr)
      #pragma unroll
      for (int r = 0; r < 4; ++r)
        oa[mr][r] = fmaf(oaL[mr][r], LOINV, oaH[mr][r]);
    if (kq != 0) {
      #pragma unroll
      for (int mr = 0; mr < 2; ++mr)
        Rs[(((nh * 3 + (kq - 1)) * 2 + mr) * 2 + 0) * 64 + lane] = oa[mr];
    }
    __syncthreads();
    if (kq == 0) {
      #pragma unroll
      for (int q = 0; q < 3; ++q)
        #pragma unroll
        for (int mr = 0; mr < 2; ++mr)
          oa[mr] += Rs[(((nh * 3 + q) * 2 + mr) * 2 + 0) * 64 + lane];
      const int col = lane & 15;
      const f16* c1b1 = c1buf + (size_t)(BB * HH);  // buf1 = c_511
      const f16* c2b1 = c2buf + (size_t)(BB * HH);
      const f16* c3b1 = c3buf + (size_t)(BB * HH);
      const int jl = nh * 16 + col;
      const int jj = j0 + jl;
      #pragma unroll
      for (int mr = 0; mr < 2; ++mr) {
        const int rloc0 = mr * 16 + ((lane >> 4) << 2);
        #pragma unroll
        for (int r = 0; r < 4; ++r) {
          int b = dom * 32 + rloc0 + r;
          size_t off = (size_t)b * HH + jj;
          unsigned vv = (xvpS[(rloc0 + r) * 128 + 127] >> 4) & 3u;  // t = 510
          float o = 1.f / (1.f + expf(-(oa[mr][r] + GoS[vv * 32 + jl])));
          float cn = (float)c1b1[off] +
                     fmaf((float)c3b1[off], LOINV2, (float)c2b1[off] * LOINV);
          float pd = vv ? 1.f : 0.f;
          hbuf[off] = tanhf(cn) * o * pd;
        }
      }
    }
  }
}

__global__ void k_proj(const float* __restrict__ hbuf, const float* __restrict__ w_ph,
                       const float* __restrict__ b_p, float* __restrict__ pbuf) {
  int wid = (blockIdx.x << 2) | (threadIdx.x >> 6);
  int lane = threadIdx.x & 63;
  const float* hrow = hbuf + (size_t)wid * HH;
  float s[NC];
  #pragma unroll
  for (int j = 0; j < NC; ++j) s[j] = 0.f;
  for (int m = 0; m < 16; ++m) {
    int k = m * 64 + lane;
    float hv = hrow[k];
    const float* wp = w_ph + k * NC;
    #pragma unroll
    for (int j = 0; j < NC; ++j) s[j] = fmaf(hv, wp[j], s[j]);
  }
  #pragma unroll
  for (int j = 0; j < NC; ++j) {
    float vv = s[j];
    for (int off = 32; off > 0; off >>= 1) vv += __shfl_down(vv, off);
    if (lane == 0) pbuf[wid * NC + j] = vv + b_p[j];
  }
}

__global__ void k_softmax(const float* __restrict__ pbuf, float* __restrict__ out) {
  __shared__ float ps[BB][NC];
  __shared__ float lse[NC];
  int b = threadIdx.x;
  #pragma unroll
  for (int j = 0; j < NC; ++j) ps[b][j] = pbuf[b * NC + j];
  __syncthreads();
  if (b < NC) {
    float m = -1e30f;
    for (int i = 0; i < BB; ++i) m = fmaxf(m, ps[i][b]);
    float sum = 0.f;
    for (int i = 0; i < BB; ++i) sum += expf(ps[i][b] - m);
    lse[b] = m + logf(sum);
  }
  __syncthreads();
  #pragma unroll
  for (int j = 0; j < NC; ++j) out[b * NC + j] = ps[b][j] - lse[j];
}

extern "C" void kernel_launch(void* const* d_in, const int* in_sizes, int n_in,
                              void* d_out, int out_size, void* d_ws, size_t ws_size,
                              hipStream_t stream) {
  const int*   x    = (const int*)d_in[0];
  const float* emb  = (const float*)d_in[1];
  const float* w_cx = (const float*)d_in[2];
  const float* b_c  = (const float*)d_in[3];
  const float* w_ix = (const float*)d_in[4];
  const float* w_ih = (const float*)d_in[5];
  const float* b_i  = (const float*)d_in[6];
  const float* w_fx = (const float*)d_in[7];
  const float* w_fh = (const float*)d_in[8];
  const float* b_f  = (const float*)d_in[9];
  const float* w_ox = (const float*)d_in[10];
  const float* w_oh = (const float*)d_in[11];
  const float* b_o  = (const float*)d_in[12];
  const float* w_ph = (const float*)d_in[13];
  const float* b_p  = (const float*)d_in[14];

  char* ws = (char*)d_ws;
  f16* W1  = (f16*)(ws + W1_OFF);
  f16* W2  = (f16*)(ws + W2_OFF);
  f16* W3  = (f16*)(ws + W3_OFF);
  f16* Wo  = (f16*)(ws + WO_OFF);
  float* Gif = (float*)(ws + GIF_OFF);
  float* Go  = (float*)(ws + GO_OFF);
  float* Cand = (float*)(ws + CAND_OFF);
  f16* c1buf = (f16*)(ws + C1_OFF);
  f16* c2buf = (f16*)(ws + C2_OFF);
  f16* c3buf = (f16*)(ws + C3_OFF);
  float* hbuf = (float*)(ws + HBUF_OFF);
  float* pbuf = (float*)(ws + PBUF_OFF);
  unsigned* bar = (unsigned*)(ws + BAR_OFF);

  hipFuncSetAttribute((const void*)k_scan,
                      hipFuncAttributeMaxDynamicSharedMemorySize, SMEM_BYTES);

  hipMemsetAsync(c1buf, 0, (size_t)BB * HH * 2, stream);   // c_0 splits buf0 = 0
  hipMemsetAsync(c2buf, 0, (size_t)BB * HH * 2, stream);
  hipMemsetAsync(c3buf, 0, (size_t)BB * HH * 2, stream);
  hipMemsetAsync(bar, 0, 4096, stream);                    // all counters

  k_tables<<<dim3(48), dim3(256), 0, stream>>>(emb, w_ix, w_fx, w_ox, w_cx,
                                               b_i, b_f, b_o, b_c, Gif, Go, Cand);
  k_fragw<<<dim3(1024), dim3(256), 0, stream>>>(w_ih, w_fh, W1, W2, W3);
  k_frago<<<dim3(512), dim3(256), 0, stream>>>(w_oh, Wo);
  k_scan<<<dim3(256), dim3(512), SMEM_BYTES, stream>>>(W1, W2, W3, Wo, Gif, Go, Cand,
                                                       x, c1buf, c2buf, c3buf,
                                                       hbuf, bar);
  k_proj<<<dim3(64), dim3(256), 0, stream>>>(hbuf, w_ph, b_p, pbuf);
  k_softmax<<<dim3(1), dim3(256), 0, stream>>>(pbuf, (float*)d_out);
}

// Round 12
// 5904.313 us; speedup vs baseline: 2.9915x; 1.3733x over previous
//
#include <hip/hip_runtime.h>
#include <math.h>

#define BB 256
#define SS 512
#define TT 511
#define HH 1024
#define EE 512
#define NC 10

typedef _Float16 f16;
typedef __attribute__((ext_vector_type(8))) _Float16 half8;
typedef __attribute__((ext_vector_type(4))) float f32x4;

#define LOSCALE 2048.0f
#define LOINV   (1.0f / 2048.0f)
#define LOINV2  (1.0f / (2048.0f * 2048.0f))

// workspace offsets (bytes)
#define W1_OFF    0u          // f16 W1 frags [4096][64][8]   4 MB
#define W2_OFF    4194304u    // f16 W2 frags (x2048)         4 MB
#define W3_OFF    8388608u    // f16 W3 frags (x2048^2)       4 MB
#define WO_OFF    12582912u   // f16 W_oh frags [2048][64][8] 2 MB
#define GIF_OFF   14680064u   // f32 [3][2048] gx tables i,f (f64-computed)
#define GO_OFF    14704640u   // f32 [3][1024] gx table o
#define CAND_OFF  14716928u   // f32 [3][1024] sigmoid(gx_c)
#define C1_OFF    14729216u   // f16 [2][256][1024] c split 1
#define C2_OFF    15777792u   // f16 [2][256][1024] c split 2 (x2048)
#define C3_OFF    16826368u   // f16 [2][256][1024] c split 3 (x2048^2)
#define HBUF_OFF  17874944u   // f32 [256][1024]
#define PBUF_OFF  18923520u   // f32 [256][10]
#define BAR_OFF   18933760u   // barrier region (4 KB, memset each launch)

// bar layout (unsigned indices): [0]=gcnt ; [16+x*16]=xcnt[x] ; [256+d*16]=dombar[d]

// LDS: W2 128K | Rs 24K | xvp 4K | Gif 768 | Cand 384 | Go 384 | shS 16 = 161296
#define SMEM_BYTES 161296

// system-scope write-through u16 store (fallback path for impure doms only)
__device__ __forceinline__ void st16(f16* p, f16 v) {
  union { f16 h; unsigned short s; } u; u.h = v;
  unsigned w = u.s;
  asm volatile("global_store_short %0, %1, off sc0 sc1" :: "v"(p), "v"(w) : "memory");
}

// gx tables in DOUBLE precision (rounded once to f32)
__global__ void k_tables(const float* __restrict__ emb,
                         const float* __restrict__ w_ix, const float* __restrict__ w_fx,
                         const float* __restrict__ w_ox, const float* __restrict__ w_cx,
                         const float* __restrict__ b_i, const float* __restrict__ b_f,
                         const float* __restrict__ b_o, const float* __restrict__ b_c,
                         float* __restrict__ Gif, float* __restrict__ Go,
                         float* __restrict__ Cand) {
  int idx = blockIdx.x * 256 + threadIdx.x;
  if (idx >= 3 * 4096) return;
  int v = idx >> 12, g = idx & 4095;
  const float* ev = emb + v * EE;
  const float* W; float bias; float* dst; bool sig = false; int j;
  if (g < 1024)      { j = g;        W = w_ix; bias = b_i[j]; dst = Gif + v * 2048 + j; }
  else if (g < 2048) { j = g - 1024; W = w_fx; bias = b_f[j]; dst = Gif + v * 2048 + 1024 + j; }
  else if (g < 3072) { j = g - 2048; W = w_ox; bias = b_o[j]; dst = Go + v * 1024 + j; }
  else               { j = g - 3072; W = w_cx; bias = b_c[j]; dst = Cand + v * 1024 + j; sig = true; }
  double s = (double)bias;
  for (int e = 0; e < EE; ++e) s = fma((double)ev[e], (double)W[e * HH + j], s);
  if (sig) s = 1.0 / (1.0 + exp(-s));
  *dst = (float)s;
}

// W triple-split frags (exact: 11+11+11 bits >= fp32 24-bit mantissa)
// frag f = ((slice*4+kq)*4+nn)*8+kc ; element (f*64+lane)*8+e
// k = kq*256+kc*32+(lane>>4)*8+e ; col=lane&15 ; jj = slice*32+nn*8+(col&7)
__global__ void k_fragw(const float* __restrict__ w_ih, const float* __restrict__ w_fh,
                        f16* __restrict__ d1, f16* __restrict__ d2, f16* __restrict__ d3) {
  int idx = blockIdx.x * 256 + threadIdx.x;
  if (idx >= 262144) return;
  int l = idx & 63;
  int kc = (idx >> 6) & 7, nn = (idx >> 9) & 3, kq = (idx >> 11) & 3, slice = idx >> 13;
  int col = l & 15;
  int jj = slice * 32 + nn * 8 + (col & 7);
  const float* W = (col < 8) ? w_ih : w_fh;
  int k0 = kq * 256 + kc * 32 + ((l >> 4) << 3);
  half8 o1, o2, o3;
  #pragma unroll
  for (int e = 0; e < 8; ++e) {
    float w = W[(k0 + e) * HH + jj];
    f16 h1 = (f16)w;
    float r1 = (w - (float)h1) * LOSCALE;
    f16 h2 = (f16)r1;
    f16 h3 = (f16)((r1 - (float)h2) * LOSCALE);
    o1[e] = h1; o2[e] = h2; o3[e] = h3;
  }
  size_t off = (size_t)idx * 8;
  *(half8*)(d1 + off) = o1;
  *(half8*)(d2 + off) = o2;
  *(half8*)(d3 + off) = o3;
}

// W_oh single-f16 frags: f = ((slice*4+kq)*2+nf)*8+kc ; jj = slice*32+nf*16+col
__global__ void k_frago(const float* __restrict__ w_oh, f16* __restrict__ dst) {
  int idx = blockIdx.x * 256 + threadIdx.x;
  if (idx >= 131072) return;
  int l = idx & 63;
  int kc = (idx >> 6) & 7, nf = (idx >> 9) & 1, kq = (idx >> 10) & 3, slice = idx >> 12;
  int col = l & 15;
  int jj = slice * 32 + nf * 16 + col;
  int k0 = kq * 256 + kc * 32 + ((l >> 4) << 3);
  half8 out;
  #pragma unroll
  for (int e = 0; e < 8; ++e) out[e] = (f16)w_oh[(k0 + e) * HH + jj];
  *(half8*)(dst + (size_t)idx * 8) = out;
}

// Domain barrier (R11-proven): monotonic counter, agent atomics (L3, always
// fresh). Exactly 32 members per dom by construction -> can never starve.
// Acquire: pure dom -> L1-only buffer_inv; impure -> agent acquire fence.
__device__ __forceinline__ void domain_barrier(unsigned* cnt, unsigned& mygen, bool pure) {
  __syncthreads();   // drains vmcnt: all this-WG c stores ACKed in L2
  if (threadIdx.x == 0) {
    mygen += 1u;
    __hip_atomic_fetch_add(cnt, 1u, __ATOMIC_RELAXED, __HIP_MEMORY_SCOPE_AGENT);
    const unsigned target = 32u * mygen;
    while (__hip_atomic_load(cnt, __ATOMIC_RELAXED, __HIP_MEMORY_SCOPE_AGENT) < target) {
      __builtin_amdgcn_s_sleep(1);
    }
    if (pure) {
      asm volatile("buffer_inv" ::: "memory");            // L1 invalidate only
    } else {
      __builtin_amdgcn_fence(__ATOMIC_ACQUIRE, "agent");  // L1+L2 invalidate
    }
  }
  __syncthreads();
}

// persistent scan: 256 WGs x 256 thr (4 waves = kq quarters), 1 WG/CU (LDS-forced).
// 1 wave/SIMD -> 512 unified regs: W1 in VGPRs, W3+acc in AGPRs, W2 in LDS.
// Each wave covers the FULL 32x32 tile for its K-quarter -> A-loads deduplicated
// (192 KB/WG/step unique). Distributed epilogue: wave kq owns combos {2kq,2kq+1}.
// gh = c1W1 + (c2W1+c1W2)*2^-11 + (c3W1+c2W2+c1W3)*2^-22 ; c exact (triple f16).
__global__ __launch_bounds__(256, 1) void k_scan(
    const f16* __restrict__ W1g, const f16* __restrict__ W2g, const f16* __restrict__ W3g,
    const f16* __restrict__ Wo,
    const float* __restrict__ Gif, const float* __restrict__ Go,
    const float* __restrict__ Cand, const int* __restrict__ x,
    f16* c1buf, f16* c2buf, f16* c3buf,
    float* __restrict__ hbuf, unsigned* bar) {
  extern __shared__ char smem[];
  f16*   W2s  = (f16*)smem;                              // 128 KB
  f32x4* Rs   = (f32x4*)(smem + 131072);                 // 24 KB (24 slots x 64 x 16B)
  unsigned char* xvpS = (unsigned char*)(smem + 155648); // 4 KB: [32 rows][128] 2-bit packed
  float* GifS = (float*)(smem + 159744);                 // [3][2][32]
  float* CandS = (float*)(smem + 160512);                // [3][32]
  float* GoS  = (float*)(smem + 160896);                 // [3][32]
  unsigned* shS = (unsigned*)(smem + 161280);            // {dom, slice, pure}

  const int tid = threadIdx.x;
  const int lane = tid & 63;
  const int kq = tid >> 6;                 // 4 waves = K quarters
  const int akoff = ((lane >> 4) << 3);

  // --- self-organize: per-XCD slot claim -> global barrier -> XCD-sorted rank ---
  if (tid == 0) {
    unsigned xcd;
    asm volatile("s_getreg_b32 %0, hwreg(HW_REG_XCC_ID)" : "=s"(xcd));
    xcd &= 7u;
    unsigned slot = __hip_atomic_fetch_add(bar + 16 + xcd * 16, 1u,
                                           __ATOMIC_RELAXED, __HIP_MEMORY_SCOPE_AGENT);
    __hip_atomic_fetch_add(bar, 1u, __ATOMIC_RELEASE, __HIP_MEMORY_SCOPE_AGENT);
    while (__hip_atomic_load(bar, __ATOMIC_ACQUIRE, __HIP_MEMORY_SCOPE_AGENT) < 256u) {
      __builtin_amdgcn_s_sleep(1);
    }
    unsigned mybase = 0, mycnt = 0;
    for (int xx = 0; xx < 8; ++xx) {
      unsigned c = __hip_atomic_load(bar + 16 + xx * 16,
                                     __ATOMIC_RELAXED, __HIP_MEMORY_SCOPE_AGENT);
      if (xx < (int)xcd) mybase += c;
      if (xx == (int)xcd) mycnt = c;
    }
    unsigned rank = mybase + slot;
    unsigned dm = rank >> 5, sl = rank & 31u;
    unsigned dlo = dm << 5, dhi = dlo + 32u;
    unsigned pure = (mybase <= dlo && dhi <= mybase + mycnt) ? 1u : 0u;
    shS[0] = dm; shS[1] = sl; shS[2] = pure;
  }
  __syncthreads();
  const int dom = (int)shS[0];
  const int slice = (int)shS[1];
  const bool pure = shS[2] != 0u;
  const int j0 = slice << 5;
  const int rowA = dom * 32 + (lane & 15);   // A-row for mr=0; +16 for mr=1

  // --- init stashes ---
  {
    const half8* gsrc = (const half8*)(W2g + (size_t)slice * 65536);
    half8* ldst = (half8*)W2s;
    for (int i = tid; i < 8192; i += 256) ldst[i] = gsrc[i];
    for (int i = tid; i < 4096; i += 256) {              // pack x to 2 bits
      int row = i >> 7, tb = i & 127;
      const int* xp = x + (size_t)(dom * 32 + row) * SS + tb * 4;
      unsigned byte = (unsigned)(xp[0] & 3) | ((unsigned)(xp[1] & 3) << 2) |
                      ((unsigned)(xp[2] & 3) << 4) | ((unsigned)(xp[3] & 3) << 6);
      xvpS[i] = (unsigned char)byte;
    }
    for (int i = tid; i < 192; i += 256) {               // GifS[v][gate][jl]
      int v = i >> 6, gate = (i >> 5) & 1, jl = i & 31;
      GifS[i] = Gif[v * 2048 + gate * 1024 + j0 + jl];
    }
    for (int i = tid; i < 96; i += 256) {                // CandS, GoS [v][jl]
      int v = i >> 5, jl = i & 31;
      CandS[i] = Cand[v * 1024 + j0 + jl];
      GoS[i]   = Go[v * 1024 + j0 + jl];
    }
  }

  // W1, W3 in registers: per wave (kq): nn(4) x kc(8) frags each = 128+128 regs
  // (W3 + accumulators expected in AGPRs at 1 wave/SIMD unified budget)
  half8 B1[8][4], B3[8][4];
  #pragma unroll
  for (int nn = 0; nn < 4; ++nn) {
    #pragma unroll
    for (int kc = 0; kc < 8; ++kc) {
      size_t f = (((size_t)slice * 4 + kq) * 4 + nn) * 8 + kc;
      B1[kc][nn] = *(const half8*)(W1g + (f * 64 + lane) * 8);
      B3[kc][nn] = *(const half8*)(W3g + (f * 64 + lane) * 8);
    }
  }
  __syncthreads();

  const f16* w2Base = W2s + kq * 16384 + lane * 8;  // + nn*4096 + kc*512

  unsigned mygen = 0;
  unsigned* bcnt = bar + 256 + dom * 16;

  // epilogue ownership: wave kq owns combos {2kq, 2kq+1}; combo c = mr*4+nn
  const int emr  = kq >> 1;              // owned row-group
  const int enn0 = (kq & 1) << 1;        // owned nn base (nn0, nn0+1)

  for (int t = 0; t < TT; ++t) {
    const int pin = t & 1, pout = pin ^ 1;
    const f16* a1b = c1buf + (size_t)pin * (BB * HH) + rowA * HH + kq * 256 + akoff;
    const f16* a2b = c2buf + (size_t)pin * (BB * HH) + rowA * HH + kq * 256 + akoff;
    const f16* a3b = c3buf + (size_t)pin * (BB * HH) + rowA * HH + kq * 256 + akoff;
    const f16* c1in = c1buf + (size_t)pin * (BB * HH);
    const f16* c2in = c2buf + (size_t)pin * (BB * HH);
    const f16* c3in = c3buf + (size_t)pin * (BB * HH);
    f16* c1out = c1buf + (size_t)pout * (BB * HH);
    f16* c2out = c2buf + (size_t)pout * (BB * HH);
    f16* c3out = c3buf + (size_t)pout * (BB * HH);

    f32x4 accA[2][4], accB[2][4], accC[2][4];   // [mr][nn]
    #pragma unroll
    for (int mr = 0; mr < 2; ++mr)
      #pragma unroll
      for (int nn = 0; nn < 4; ++nn) {
        accA[mr][nn] = (f32x4){0.f, 0.f, 0.f, 0.f};
        accB[mr][nn] = (f32x4){0.f, 0.f, 0.f, 0.f};
        accC[mr][nn] = (f32x4){0.f, 0.f, 0.f, 0.f};
      }
    #pragma unroll
    for (int kc = 0; kc < 8; ++kc) {
      half8 a1[2], a2[2], a3[2];
      #pragma unroll
      for (int mr = 0; mr < 2; ++mr) {
        a1[mr] = *(const half8*)(a1b + mr * 16 * HH + kc * 32);
        a2[mr] = *(const half8*)(a2b + mr * 16 * HH + kc * 32);
        a3[mr] = *(const half8*)(a3b + mr * 16 * HH + kc * 32);
      }
      #pragma unroll
      for (int nn = 0; nn < 4; ++nn) {
        half8 w2 = *(const half8*)(w2Base + nn * 4096 + kc * 512);
        #pragma unroll
        for (int mr = 0; mr < 2; ++mr) {
          accA[mr][nn] = __builtin_amdgcn_mfma_f32_16x16x32_f16(a1[mr], B1[kc][nn], accA[mr][nn], 0, 0, 0);
          accB[mr][nn] = __builtin_amdgcn_mfma_f32_16x16x32_f16(a2[mr], B1[kc][nn], accB[mr][nn], 0, 0, 0);
          accB[mr][nn] = __builtin_amdgcn_mfma_f32_16x16x32_f16(a1[mr], w2, accB[mr][nn], 0, 0, 0);
          accC[mr][nn] = __builtin_amdgcn_mfma_f32_16x16x32_f16(a3[mr], B1[kc][nn], accC[mr][nn], 0, 0, 0);
          accC[mr][nn] = __builtin_amdgcn_mfma_f32_16x16x32_f16(a2[mr], w2, accC[mr][nn], 0, 0, 0);
          accC[mr][nn] = __builtin_amdgcn_mfma_f32_16x16x32_f16(a1[mr], B3[kc][nn], accC[mr][nn], 0, 0, 0);
        }
      }
    }
    f32x4 gh[2][4];
    #pragma unroll
    for (int mr = 0; mr < 2; ++mr)
      #pragma unroll
      for (int nn = 0; nn < 4; ++nn)
        #pragma unroll
        for (int r = 0; r < 4; ++r)
          gh[mr][nn][r] = fmaf(accC[mr][nn][r], LOINV2,
                               fmaf(accB[mr][nn][r], LOINV, accA[mr][nn][r]));
    // write non-owned partials: slot = c*3 + writer-index
    #pragma unroll
    for (int mr = 0; mr < 2; ++mr)
      #pragma unroll
      for (int nn = 0; nn < 4; ++nn) {
        int c = mr * 4 + nn, o = c >> 1;
        if (o != kq) {
          int wi = (kq > o) ? (kq - 1) : kq;
          Rs[(c * 3 + wi) * 64 + lane] = gh[mr][nn];
        }
      }
    __syncthreads();
    // distributed epilogue: this wave's 2 owned combos (mr=emr, nn=enn0/enn0+1)
    {
      f32x4 g2[2];
      #pragma unroll
      for (int q = 0; q < 2; ++q) {
        int c = emr * 4 + enn0 + q;
        f32x4 g = gh[emr][enn0 + q];
        #pragma unroll
        for (int s = 0; s < 3; ++s) g += Rs[(c * 3 + s) * 64 + lane];
        g2[q] = g;
      }
      const int col = lane & 15;
      const bool isI = col < 8;
      const int jcol = col & 7;
      const int gsel = isI ? 0 : 1;
      const int tb = t >> 2, tsh = (t & 3) << 1;
      const int rloc0 = emr * 16 + ((lane >> 4) << 2);     // domain-local row base
      unsigned v[4];
      #pragma unroll
      for (int r = 0; r < 4; ++r)
        v[r] = (xvpS[(rloc0 + r) * 128 + tb] >> tsh) & 3u;
      #pragma unroll
      for (int q = 0; q < 2; ++q) {
        const int nn = enn0 + q;
        const int jl = nn * 8 + jcol;                      // local col 0..31
        const int jj = j0 + jl;
        float sg[4];
        #pragma unroll
        for (int r = 0; r < 4; ++r) {
          float pre = g2[q][r] + GifS[(v[r] * 2 + gsel) * 32 + jl];
          sg[r] = 1.f / (1.f + expf(-pre));
        }
        float ot[4];
        #pragma unroll
        for (int r = 0; r < 4; ++r) ot[r] = __shfl_xor(sg[r], 8);
        const int rlo = isI ? 0 : 2;
        #pragma unroll
        for (int p = 0; p < 2; ++p) {
          int r = rlo + p;
          int b = dom * 32 + rloc0 + r;
          size_t off = (size_t)b * HH + jj;
          float iv = isI ? sg[r] : ot[r];
          float fv = isI ? ot[r] : sg[r];
          float cd = CandS[v[r] * 32 + jl];
          float co = (float)c1in[off] +
                     fmaf((float)c3in[off], LOINV2, (float)c2in[off] * LOINV);
          float cn = fmaf(cd, iv, co * fv);
          f16 h1 = (f16)cn;
          float r1 = (cn - (float)h1) * LOSCALE;
          f16 h2 = (f16)r1;
          f16 h3 = (f16)((r1 - (float)h2) * LOSCALE);
          if (pure) {
            c1out[off] = h1;        // plain stores: dirty in XCD-local L2
            c2out[off] = h2;
            c3out[off] = h3;
          } else {
            st16(c1out + off, h1);  // fallback: write-through to coherence point
            st16(c2out + off, h2);
            st16(c3out + off, h3);
          }
        }
      }
    }
    domain_barrier(bcnt, mygen, pure);
  }

  // ---- last step: o gate from c_510 (buf0, hi+mid), h = tanh(c_511)*o*pad
  {
    const f16* a1b = c1buf + rowA * HH + kq * 256 + akoff;  // buf0 = c_510
    const f16* a2b = c2buf + rowA * HH + kq * 256 + akoff;
    f32x4 oaH[2][2], oaL[2][2];   // [mr][nf]
    #pragma unroll
    for (int mr = 0; mr < 2; ++mr)
      #pragma unroll
      for (int nf = 0; nf < 2; ++nf) {
        oaH[mr][nf] = (f32x4){0.f, 0.f, 0.f, 0.f};
        oaL[mr][nf] = (f32x4){0.f, 0.f, 0.f, 0.f};
      }
    #pragma unroll
    for (int kc = 0; kc < 8; ++kc) {
      half8 a1[2], a2[2];
      #pragma unroll
      for (int mr = 0; mr < 2; ++mr) {
        a1[mr] = *(const half8*)(a1b + mr * 16 * HH + kc * 32);
        a2[mr] = *(const half8*)(a2b + mr * 16 * HH + kc * 32);
      }
      #pragma unroll
      for (int nf = 0; nf < 2; ++nf) {
        size_t f = (((size_t)slice * 4 + kq) * 2 + nf) * 8 + kc;
        half8 bw = *(const half8*)(Wo + (f * 64 + lane) * 8);
        #pragma unroll
        for (int mr = 0; mr < 2; ++mr) {
          oaH[mr][nf] = __builtin_amdgcn_mfma_f32_16x16x32_f16(a1[mr], bw, oaH[mr][nf], 0, 0, 0);
          oaL[mr][nf] = __builtin_amdgcn_mfma_f32_16x16x32_f16(a2[mr], bw, oaL[mr][nf], 0, 0, 0);
        }
      }
    }
    f32x4 oa[2][2];
    #pragma unroll
    for (int mr = 0; mr < 2; ++mr)
      #pragma unroll
      for (int nf = 0; nf < 2; ++nf)
        #pragma unroll
        for (int r = 0; r < 4; ++r)
          oa[mr][nf][r] = fmaf(oaL[mr][nf][r], LOINV, oaH[mr][nf][r]);
    // distributed: wave kq owns combo cc = kq = mr*2+nf
    #pragma unroll
    for (int mr = 0; mr < 2; ++mr)
      #pragma unroll
      for (int nf = 0; nf < 2; ++nf) {
        int cc = mr * 2 + nf;
        if (cc != kq) {
          int wi = (kq > cc) ? (kq - 1) : kq;
          Rs[(cc * 3 + wi) * 64 + lane] = oa[mr][nf];
        }
      }
    __syncthreads();
    {
      const int mr = kq >> 1, nf = kq & 1;
      f32x4 o4 = oa[mr][nf];
      #pragma unroll
      for (int s = 0; s < 3; ++s) o4 += Rs[(kq * 3 + s) * 64 + lane];
      const int col = lane & 15;
      const f16* c1b1 = c1buf + (size_t)(BB * HH);  // buf1 = c_511
      const f16* c2b1 = c2buf + (size_t)(BB * HH);
      const f16* c3b1 = c3buf + (size_t)(BB * HH);
      const int jl = nf * 16 + col;
      const int jj = j0 + jl;
      const int rloc0 = mr * 16 + ((lane >> 4) << 2);
      #pragma unroll
      for (int r = 0; r < 4; ++r) {
        int b = dom * 32 + rloc0 + r;
        size_t off = (size_t)b * HH + jj;
        unsigned vv = (xvpS[(rloc0 + r) * 128 + 127] >> 4) & 3u;  // t = 510
        float o = 1.f / (1.f + expf(-(o4[r] + GoS[vv * 32 + jl])));
        float cn = (float)c1b1[off] +
                   fmaf((float)c3b1[off], LOINV2, (float)c2b1[off] * LOINV);
        float pd = vv ? 1.f : 0.f;
        hbuf[off] = tanhf(cn) * o * pd;
      }
    }
  }
}

__global__ void k_proj(const float* __restrict__ hbuf, const float* __restrict__ w_ph,
                       const float* __restrict__ b_p, float* __restrict__ pbuf) {
  int wid = (blockIdx.x << 2) | (threadIdx.x >> 6);
  int lane = threadIdx.x & 63;
  const float* hrow = hbuf + (size_t)wid * HH;
  float s[NC];
  #pragma unroll
  for (int j = 0; j < NC; ++j) s[j] = 0.f;
  for (int m = 0; m < 16; ++m) {
    int k = m * 64 + lane;
    float hv = hrow[k];
    const float* wp = w_ph + k * NC;
    #pragma unroll
    for (int j = 0; j < NC; ++j) s[j] = fmaf(hv, wp[j], s[j]);
  }
  #pragma unroll
  for (int j = 0; j < NC; ++j) {
    float vv = s[j];
    for (int off = 32; off > 0; off >>= 1) vv += __shfl_down(vv, off);
    if (lane == 0) pbuf[wid * NC + j] = vv + b_p[j];
  }
}

__global__ void k_softmax(const float* __restrict__ pbuf, float* __restrict__ out) {
  __shared__ float ps[BB][NC];
  __shared__ float lse[NC];
  int b = threadIdx.x;
  #pragma unroll
  for (int j = 0; j < NC; ++j) ps[b][j] = pbuf[b * NC + j];
  __syncthreads();
  if (b < NC) {
    float m = -1e30f;
    for (int i = 0; i < BB; ++i) m = fmaxf(m, ps[i][b]);
    float sum = 0.f;
    for (int i = 0; i < BB; ++i) sum += expf(ps[i][b] - m);
    lse[b] = m + logf(sum);
  }
  __syncthreads();
  #pragma unroll
  for (int j = 0; j < NC; ++j) out[b * NC + j] = ps[b][j] - lse[j];
}

extern "C" void kernel_launch(void* const* d_in, const int* in_sizes, int n_in,
                              void* d_out, int out_size, void* d_ws, size_t ws_size,
                              hipStream_t stream) {
  const int*   x    = (const int*)d_in[0];
  const float* emb  = (const float*)d_in[1];
  const float* w_cx = (const float*)d_in[2];
  const float* b_c  = (const float*)d_in[3];
  const float* w_ix = (const float*)d_in[4];
  const float* w_ih = (const float*)d_in[5];
  const float* b_i  = (const float*)d_in[6];
  const float* w_fx = (const float*)d_in[7];
  const float* w_fh = (const float*)d_in[8];
  const float* b_f  = (const float*)d_in[9];
  const float* w_ox = (const float*)d_in[10];
  const float* w_oh = (const float*)d_in[11];
  const float* b_o  = (const float*)d_in[12];
  const float* w_ph = (const float*)d_in[13];
  const float* b_p  = (const float*)d_in[14];

  char* ws = (char*)d_ws;
  f16* W1  = (f16*)(ws + W1_OFF);
  f16* W2  = (f16*)(ws + W2_OFF);
  f16* W3  = (f16*)(ws + W3_OFF);
  f16* Wo  = (f16*)(ws + WO_OFF);
  float* Gif = (float*)(ws + GIF_OFF);
  float* Go  = (float*)(ws + GO_OFF);
  float* Cand = (float*)(ws + CAND_OFF);
  f16* c1buf = (f16*)(ws + C1_OFF);
  f16* c2buf = (f16*)(ws + C2_OFF);
  f16* c3buf = (f16*)(ws + C3_OFF);
  float* hbuf = (float*)(ws + HBUF_OFF);
  float* pbuf = (float*)(ws + PBUF_OFF);
  unsigned* bar = (unsigned*)(ws + BAR_OFF);

  hipFuncSetAttribute((const void*)k_scan,
                      hipFuncAttributeMaxDynamicSharedMemorySize, SMEM_BYTES);

  hipMemsetAsync(c1buf, 0, (size_t)BB * HH * 2, stream);   // c_0 splits buf0 = 0
  hipMemsetAsync(c2buf, 0, (size_t)BB * HH * 2, stream);
  hipMemsetAsync(c3buf, 0, (size_t)BB * HH * 2, stream);
  hipMemsetAsync(bar, 0, 4096, stream);                    // all counters

  k_tables<<<dim3(48), dim3(256), 0, stream>>>(emb, w_ix, w_fx, w_ox, w_cx,
                                               b_i, b_f, b_o, b_c, Gif, Go, Cand);
  k_fragw<<<dim3(1024), dim3(256), 0, stream>>>(w_ih, w_fh, W1, W2, W3);
  k_frago<<<dim3(512), dim3(256), 0, stream>>>(w_oh, Wo);
  k_scan<<<dim3(256), dim3(256), SMEM_BYTES, stream>>>(W1, W2, W3, Wo, Gif, Go, Cand,
                                                       x, c1buf, c2buf, c3buf,
                                                       hbuf, bar);
  k_proj<<<dim3(64), dim3(256), 0, stream>>>(hbuf, w_ph, b_p, pbuf);
  k_softmax<<<dim3(1), dim3(256), 0, stream>>>(pbuf, (float*)d_out);
}